// Round 10
// baseline (231.901 us; speedup 1.0000x reference)
//
#include <hip/hip_runtime.h>

constexpr int SEQ = 2048;
constexpr int DM = 1024;
constexpr int NH = 16;
constexpr int BATCH = 2;
constexpr int MTOT = BATCH * SEQ;   // 4096

typedef __bf16 bf16x8 __attribute__((ext_vector_type(8)));
typedef __bf16 bf16x4 __attribute__((ext_vector_type(4)));
typedef float f32x4 __attribute__((ext_vector_type(4)));

#define MFMA16(a, b, c) __builtin_amdgcn_mfma_f32_16x16x32_bf16((a), (b), (c), 0, 0, 0)

__device__ __forceinline__ void async_copy16(const void* g, void* l) {
  __builtin_amdgcn_global_load_lds((const __attribute__((address_space(1))) void*)g,
                                   (__attribute__((address_space(3))) void*)l, 16, 0, 0);
}

// T1 bijective XCD swizzle (R7): contiguous block chunks per XCD. nwg%8==0.
__device__ __forceinline__ void xcd_swizzle(int& bx, int& by) {
  const int gx = gridDim.x;
  const int nwg = gx * gridDim.y;
  const int bid = blockIdx.y * gx + blockIdx.x;
  const int cpx = nwg >> 3;
  const int v = (bid & 7) * cpx + (bid >> 3);
  by = v / gx;
  bx = v - by * gx;
}

__global__ void sentinel_fill(float* out, int n) {
  int i = blockIdx.x * blockDim.x + threadIdx.x;
  for (; i < n; i += gridDim.x * blockDim.x) out[i] = 0.25f;
}

// one-shot fp32 -> bf16 conversion of x, w_qkv, w_o
__global__ __launch_bounds__(256) void cvt_all(const float* __restrict__ x,
                                               const float* __restrict__ wq,
                                               const float* __restrict__ wo,
                                               __bf16* __restrict__ xb,
                                               __bf16* __restrict__ wqb,
                                               __bf16* __restrict__ wob) {
  const long i = (long)(blockIdx.x * 256 + threadIdx.x) * 8;
  const float* src;
  __bf16* dst;
  long off;
  if (i < 4194304) { src = x; dst = xb; off = i; }
  else if (i < 7340032) { src = wq; dst = wqb; off = i - 4194304; }
  else { src = wo; dst = wob; off = i - 7340032; }
  f32x4 lo = *(const f32x4*)(src + off);
  f32x4 hi = *(const f32x4*)(src + off + 4);
  bf16x8 r;
#pragma unroll
  for (int j = 0; j < 4; ++j) { r[j] = (__bf16)lo[j]; r[4 + j] = (__bf16)hi[j]; }
  *(bf16x8*)(dst + off) = r;
}

// R10: 256x256-tile GEMM for gemm1 (C[M,N]=A[M,K]*B[N,K]^T, bf16).
// BK=64, 512 threads = 8 waves (2M x 4N), per-wave 128x64 output (acc 8x4,
// 64 MFMA/K-tile/wave). One vmcnt-drain per K-TILE (amortized over 4x more
// MFMA than the 128^2 tile, whose per-16-MFMA drain capped it at ~400 TF --
// R8 showed 1-step counted lookahead doesn't fix that structure). Staging for
// kt+1 is issued FIRST each iteration -> ~600+ cyc MFMA cover before drain.
// LDS 128 KB (2 x (As 32K + Bs 32K)), 1 block/CU, grid 192 blocks balanced.
// Indexing is the verified gemm_bt pattern scaled to 64-col rows.
template <typename OutT>
__global__ __launch_bounds__(512, 1) void gemm256(const __bf16* __restrict__ A,
                                                  const __bf16* __restrict__ B,
                                                  OutT* __restrict__ C,
                                                  int M, int N, int K, int lda,
                                                  float nanSig) {
  __shared__ alignas(16) __bf16 As[2][256 * 64];
  __shared__ alignas(16) __bf16 Bs[2][256 * 64];
  const int tid = threadIdx.x;
  const int lane = tid & 63;
  const int wave = tid >> 6;        // 0..7
  const int lr = lane & 15;
  const int quad = lane >> 4;
  const int wm = (wave >> 2) * 128; // M-half per wave-pair
  const int wn = (wave & 3) * 64;   // N-quarter per wave
  int bx, by;
  xcd_swizzle(bx, by);
  const int m0 = by * 256;
  const int n0 = bx * 256;

  // staging: round r covers rows r*64..r*64+63; wave w covers rows +w*8..+7;
  // lane i -> row +(i>>3), col (i&7)*8. LDS dest wave-uniform (lane offset
  // i*16B == (i>>3)*64 + (i&7)*8 elements, identity since row stride = 64).
  const int srow = wave * 8 + (lane >> 3);
  const int scol = (lane & 7) * 8;
  const __bf16* gA = A + (long)(m0 + srow) * lda + scol;
  const __bf16* gB = B + (long)(n0 + srow) * lda + scol;  // ldb == K == lda

  f32x4 acc[8][4];
#pragma unroll
  for (int i = 0; i < 8; ++i)
#pragma unroll
    for (int j = 0; j < 4; ++j) acc[i][j] = (f32x4){0.f, 0.f, 0.f, 0.f};

  auto stage = [&](int bi, int k0) {
#pragma unroll
    for (int r = 0; r < 4; ++r)
      async_copy16(gA + (long)r * 64 * lda + k0, &As[bi][(r * 64 + wave * 8) * 64]);
#pragma unroll
    for (int r = 0; r < 4; ++r)
      async_copy16(gB + (long)r * 64 * lda + k0, &Bs[bi][(r * 64 + wave * 8) * 64]);
  };

  const int nt = K >> 6;
  stage(0, 0);
  __syncthreads();  // drain + barrier: tile 0 staged

  for (int kt = 0; kt < nt; ++kt) {
    const int c = kt & 1;
    if (kt + 1 < nt) stage(c ^ 1, (kt + 1) * 64);  // issue early: full-iter cover

    bf16x8 bfr[2][4];
#pragma unroll
    for (int kh = 0; kh < 2; ++kh)
#pragma unroll
      for (int j = 0; j < 4; ++j)
        bfr[kh][j] = *(const bf16x8*)&Bs[c][(wn + j * 16 + lr) * 64 + kh * 32 + quad * 8];
    __builtin_amdgcn_s_setprio(1);
#pragma unroll
    for (int i = 0; i < 8; ++i) {
      bf16x8 af0 = *(const bf16x8*)&As[c][(wm + i * 16 + lr) * 64 + quad * 8];
      bf16x8 af1 = *(const bf16x8*)&As[c][(wm + i * 16 + lr) * 64 + 32 + quad * 8];
#pragma unroll
      for (int j = 0; j < 4; ++j) {
        acc[i][j] = MFMA16(af0, bfr[0][j], acc[i][j]);
        acc[i][j] = MFMA16(af1, bfr[1][j], acc[i][j]);
      }
    }
    __builtin_amdgcn_s_setprio(0);
    __syncthreads();  // one drain+barrier per K-tile (WAR on buf c, RAW on c^1)
  }

#pragma unroll
  for (int i = 0; i < 8; ++i) {
    const int row = m0 + wm + i * 16 + quad * 4;
#pragma unroll
    for (int j = 0; j < 4; ++j) {
      const int col = n0 + wn + j * 16 + lr;
#pragma unroll
      for (int r = 0; r < 4; ++r) {
        float v = acc[i][j][r];
        if (!(v == v)) v = nanSig;
        C[(long)(row + r) * N + col] = (OutT)v;
      }
    }
  }
}

// 64x128-tile variant for gemm2 (R7/R8, kept): 512 blocks = 2/CU,
// counted-vmcnt 3-buffer pipeline. LDS 36 KB.
template <typename OutT>
__global__ __launch_bounds__(256) void gemm_bt64(const __bf16* __restrict__ A,
                                                 const __bf16* __restrict__ B,
                                                 OutT* __restrict__ C,
                                                 int M, int N, int K, int lda,
                                                 float nanSig) {
  __shared__ alignas(16) __bf16 As[3][64 * 32];
  __shared__ alignas(16) __bf16 Bs[3][128 * 32];
  const int tid = threadIdx.x;
  const int lane = tid & 63;
  const int wave = tid >> 6;
  const int lr = lane & 15;
  const int quad = lane >> 4;
  const int wm = (wave >> 1) * 32;
  const int wn = (wave & 1) * 64;
  int bx, by;
  xcd_swizzle(bx, by);
  const int m0 = by * 64;
  const int n0 = bx * 128;

  const int ra = tid >> 2;          // 0..63
  const int ca = (tid & 3) * 8;
  const __bf16* gA0 = A + (long)(m0 + ra) * lda + ca;
  const __bf16* gB0 = B + (long)(n0 + ra) * K + ca;
  const __bf16* gB1 = B + (long)(n0 + 64 + ra) * K + ca;

  f32x4 acc[2][4];
#pragma unroll
  for (int i = 0; i < 2; ++i)
#pragma unroll
    for (int j = 0; j < 4; ++j) acc[i][j] = (f32x4){0.f, 0.f, 0.f, 0.f};

  auto stage = [&](int bi, int k0) {
    async_copy16(gA0 + k0, &As[bi][wave * 512]);
    async_copy16(gB0 + k0, &Bs[bi][wave * 512]);
    async_copy16(gB1 + k0, &Bs[bi][2048 + wave * 512]);
  };

  const int nt = K >> 5;
  stage(0, 0);
  if (nt > 1) stage(1, 32);

  int cur = 0;
  for (int t = 0; t < nt; ++t) {
    if (t + 1 < nt) {
      asm volatile("s_waitcnt vmcnt(3)" ::: "memory");
    } else {
      asm volatile("s_waitcnt vmcnt(0)" ::: "memory");
    }
    __builtin_amdgcn_sched_barrier(0);
    __builtin_amdgcn_s_barrier();
    if (t + 2 < nt) stage(cur == 0 ? 2 : cur - 1, (t + 2) * 32);

    bf16x8 af[2], bfr[4];
#pragma unroll
    for (int i = 0; i < 2; ++i)
      af[i] = *(const bf16x8*)&As[cur][(wm + i * 16 + lr) * 32 + quad * 8];
#pragma unroll
    for (int j = 0; j < 4; ++j)
      bfr[j] = *(const bf16x8*)&Bs[cur][(wn + j * 16 + lr) * 32 + quad * 8];
    __builtin_amdgcn_s_setprio(1);
#pragma unroll
    for (int i = 0; i < 2; ++i)
#pragma unroll
      for (int j = 0; j < 4; ++j) acc[i][j] = MFMA16(af[i], bfr[j], acc[i][j]);
    __builtin_amdgcn_s_setprio(0);
    cur = (cur == 2) ? 0 : cur + 1;
  }

#pragma unroll
  for (int i = 0; i < 2; ++i) {
    const int row = m0 + wm + i * 16 + quad * 4;
#pragma unroll
    for (int j = 0; j < 4; ++j) {
      const int col = n0 + wn + j * 16 + lr;
#pragma unroll
      for (int r = 0; r < 4; ++r) {
        float v = acc[i][j][r];
        if (!(v == v)) v = nanSig;
        C[(long)(row + r) * N + col] = (OutT)v;
      }
    }
  }
}

// SLOW fallback GEMM (inline fp32 cvt, verified R9).
template <int F32>
__device__ __forceinline__ bf16x8 load_cvt8(const void* base, long off) {
  if constexpr (F32) {
    const float* p = (const float*)base + off;
    f32x4 lo = *(const f32x4*)p;
    f32x4 hi = *(const f32x4*)(p + 4);
    bf16x8 r;
#pragma unroll
    for (int j = 0; j < 4; ++j) { r[j] = (__bf16)lo[j]; r[4 + j] = (__bf16)hi[j]; }
    return r;
  } else {
    return *(const bf16x8*)((const __bf16*)base + off);
  }
}

template <int AF32, int BF32, typename OutT>
__global__ __launch_bounds__(256) void gemm_nt(const void* __restrict__ Av,
                                               const void* __restrict__ Bv,
                                               OutT* __restrict__ C,
                                               int M, int N, int K, int lda,
                                               float nanSig) {
  __shared__ alignas(16) __bf16 As[128 * 32];
  __shared__ alignas(16) __bf16 Bs[128 * 32];
  const int tid = threadIdx.x;
  const int lane = tid & 63;
  const int wave = tid >> 6;
  const int lr = lane & 15;
  const int quad = lane >> 4;
  const int wm = (wave >> 1) * 64;
  const int wn = (wave & 1) * 64;
  const int m0 = blockIdx.y * 128;
  const int n0 = blockIdx.x * 128;

  const int r0 = tid >> 2;
  const int r1 = 64 + (tid >> 2);
  const int cc = (tid & 3) * 8;
  const long aBase0 = (long)(m0 + r0) * lda + cc;
  const long aBase1 = (long)(m0 + r1) * lda + cc;
  const long bBase0 = (long)(n0 + r0) * K + cc;
  const long bBase1 = (long)(n0 + r1) * K + cc;
  __bf16* lA0 = &As[r0 * 32 + cc];
  __bf16* lA1 = &As[r1 * 32 + cc];
  __bf16* lB0 = &Bs[r0 * 32 + cc];
  __bf16* lB1 = &Bs[r1 * 32 + cc];

  f32x4 acc[4][4];
#pragma unroll
  for (int i = 0; i < 4; ++i)
#pragma unroll
    for (int j = 0; j < 4; ++j) acc[i][j] = (f32x4){0.f, 0.f, 0.f, 0.f};

  for (int k0 = 0; k0 < K; k0 += 32) {
    bf16x8 va0 = load_cvt8<AF32>(Av, aBase0 + k0);
    bf16x8 va1 = load_cvt8<AF32>(Av, aBase1 + k0);
    bf16x8 vb0 = load_cvt8<BF32>(Bv, bBase0 + k0);
    bf16x8 vb1 = load_cvt8<BF32>(Bv, bBase1 + k0);
    __syncthreads();
    *(bf16x8*)lA0 = va0;
    *(bf16x8*)lA1 = va1;
    *(bf16x8*)lB0 = vb0;
    *(bf16x8*)lB1 = vb1;
    __syncthreads();
    bf16x8 af[4], bfr[4];
#pragma unroll
    for (int i = 0; i < 4; ++i) af[i] = *(const bf16x8*)&As[(wm + i * 16 + lr) * 32 + quad * 8];
#pragma unroll
    for (int j = 0; j < 4; ++j) bfr[j] = *(const bf16x8*)&Bs[(wn + j * 16 + lr) * 32 + quad * 8];
#pragma unroll
    for (int i = 0; i < 4; ++i)
#pragma unroll
      for (int j = 0; j < 4; ++j) acc[i][j] = MFMA16(af[i], bfr[j], acc[i][j]);
  }

#pragma unroll
  for (int i = 0; i < 4; ++i) {
    const int row = m0 + wm + i * 16 + quad * 4;
#pragma unroll
    for (int j = 0; j < 4; ++j) {
      const int col = n0 + wn + j * 16 + lr;
#pragma unroll
      for (int r = 0; r < 4; ++r) {
        float v = acc[i][j][r];
        if (!(v == v)) v = nanSig;
        C[(long)(row + r) * N + col] = (OutT)v;
      }
    }
  }
}

// Flash causal attention, S^T form. R9 QG-PER-WAVE SPLIT (kept, untouched —
// R9 confirmed attn is at its structural plateau: occupancy 19->31% with time
// flat, so the per-tile staging/barrier convoy is the floor). 512 threads;
// waves 0-3 own q-tile B, waves 4-7 own q-tile A. Grid 16x16x2 = 512 blocks.
__global__ __launch_bounds__(512, 4) void attn_fwd(__bf16* __restrict__ qkv) {
  const int pi = blockIdx.x;      // 0..15: pair id
  const int h = blockIdx.y;
  const int b = blockIdx.z;
  const int q0A = pi * 64;
  const int q0B = (31 - pi) * 64;
  const int tid = threadIdx.x;
  const int lane = tid & 63;
  const int wave = tid >> 6;      // 0..7
  const int grp = wave >> 2;      // 0: q-tile B (full range), 1: q-tile A
  const int q0X = grp ? q0A : q0B;
  const int lr = lane & 15;
  const int quad = lane >> 4;
  const int wq = (wave & 3) * 16;
  const int qi = q0X + wq + lr;

  __shared__ alignas(16) __bf16 Ks[2][64 * 72];  // K rows [kv][d], double-buffered
  __shared__ alignas(16) __bf16 Vt[2][64 * 72];  // V^T [d][kv^swz], double-buffered
  __shared__ alignas(16) __bf16 Pq[128 * 72];    // P [wave*16 + q][kv]

  __bf16* pqw = &Pq[wave * 16 * 72];
  const long base = (long)b * SEQ * 3072;

  // Q as B-operand fragments (one q-group per wave)
  bf16x8 b_q[2];
  {
    const long rowoff = base + (long)qi * 3072 + h * 64;
    b_q[0] = *(const bf16x8*)(qkv + rowoff + quad * 8);
    b_q[1] = *(const bf16x8*)(qkv + rowoff + 32 + quad * 8);
  }

  const float NEGS = -30000.f;
  const float SC = 0.18033688f;  // 0.125 * log2(e): softmax in exp2 domain
  float m_i = NEGS, l_i = 0.f;
  f32x4 o_acc[4];
#pragma unroll
  for (int dt = 0; dt < 4; ++dt) o_acc[dt] = (f32x4){0.f, 0.f, 0.f, 0.f};

  // staging thread geometry (512 stagers: 1 row each)
  const int r_ = tid >> 3;            // 0..63
  const int col_ = (tid & 7) * 8;     // 0..56
  const int l8 = tid & 7;
  const int sw = (l8 & 3) << 3;       // Vt swizzle amount for this thread's cols
  const bool oddr = (tid >> 3) & 1;
  const int jb = oddr ? 4 : 0;

  const int Tb = 32 - pi;             // B's full causal range in KV tiles, >= 17

  bf16x8 kreg, vreg;
  auto loadTile = [&](int t) {
    const long ro = base + ((long)t * 64 + r_) * 3072 + h * 64 + col_;
    kreg = *(const bf16x8*)(qkv + ro + 1024);
    vreg = *(const bf16x8*)(qkv + ro + 2048);
  };
  auto stageTile = [&](int bi) {
    __bf16* ks = &Ks[bi][0];
    __bf16* vt = &Vt[bi][0];
    // K row -> LDS (b128)
    *(bf16x8*)&ks[r_ * 72 + col_] = kreg;
    // V^T via pair-transpose + swizzle (b32 writes, 2-way banks = free)
    const int rr = (r_ & ~1) ^ sw;
    int vd[4], od[4];
    __builtin_memcpy(vd, &vreg, 16);
#pragma unroll
    for (int i = 0; i < 4; ++i) od[i] = __shfl_xor(vd[i], 8);
#pragma unroll
    for (int i = 0; i < 4; ++i) {
      const int j = jb + i;
      const int a = vd[j >> 1], bb = od[j >> 1];
      const int lo = oddr ? bb : a;
      const int hi = oddr ? a : bb;
      const int pair = (j & 1) ? (int)(((unsigned)lo >> 16) | (hi & 0xffff0000))
                               : (int)((lo & 0xffff) | (hi << 16));
      *(int*)&vt[(col_ + j) * 72 + rr] = pair;
    }
  };

  // prologue: stage tile 0 into buf0, issue loads for tile 1
  loadTile(0);
  stageTile(0);
  loadTile(1);  // Tb >= 17, always valid
  __syncthreads();

  for (int t = 0; t < Tb; ++t) {
    const int cur = t & 1;
    const int kv0 = t * 64;
    // wave-uniform: B-waves always active; A-waves while kv in causal range
    const bool act = (grp == 0) || (kv0 <= q0A + wq + 15);

    // S^T = K * Q^T from Ks[cur]
    f32x4 st[4];
#pragma unroll
    for (int kt = 0; kt < 4; ++kt) st[kt] = (f32x4){0.f, 0.f, 0.f, 0.f};
    if (act) {
      __builtin_amdgcn_s_setprio(1);
#pragma unroll
      for (int ks = 0; ks < 2; ++ks) {
        bf16x8 ak[4];
#pragma unroll
        for (int kt = 0; kt < 4; ++kt)
          ak[kt] = *(const bf16x8*)&Ks[cur][(kt * 16 + lr) * 72 + ks * 32 + quad * 8];
#pragma unroll
        for (int kt = 0; kt < 4; ++kt) st[kt] = MFMA16(ak[kt], b_q[ks], st[kt]);
      }
      __builtin_amdgcn_s_setprio(0);
    }

    // stage tile t+1 into the other buffer (overlaps with softmax below),
    // then issue global loads for tile t+2 (consumed by next iter's stage).
    if (t + 1 < Tb) stageTile(cur ^ 1);
    if (t + 2 < Tb) loadTile(t + 2);

    if (act) {
      // scale (exp2 domain) + causal mask
      if (kv0 + 64 <= q0X + wq) {
#pragma unroll
        for (int kt = 0; kt < 4; ++kt)
#pragma unroll
          for (int r = 0; r < 4; ++r) st[kt][r] *= SC;
      } else {
#pragma unroll
        for (int kt = 0; kt < 4; ++kt) {
          const int d0 = kv0 + kt * 16 + quad * 4 - qi;
#pragma unroll
          for (int r = 0; r < 4; ++r)
            st[kt][r] = (d0 + r <= 0) ? st[kt][r] * SC : NEGS;
        }
      }
      // online softmax (in-lane over 16 kv + 2 shfl)
      float mx = st[0][0];
#pragma unroll
      for (int kt = 0; kt < 4; ++kt)
#pragma unroll
        for (int r = 0; r < 4; ++r) mx = fmaxf(mx, st[kt][r]);
      mx = fmaxf(mx, __shfl_xor(mx, 16));
      mx = fmaxf(mx, __shfl_xor(mx, 32));
      // T13 defer-rescale: keep old max while growth <= 8 (P bounded by 2^8)
      const bool noresc = __all(mx - m_i <= 8.f);
      const float mnew = noresc ? m_i : fmaxf(m_i, mx);
      float rs = 0.f;
#pragma unroll
      for (int kt = 0; kt < 4; ++kt)
#pragma unroll
        for (int r = 0; r < 4; ++r) {
          const float p = exp2f(st[kt][r] - mnew);
          st[kt][r] = p;
          rs += p;
        }
      rs += __shfl_xor(rs, 16);
      rs += __shfl_xor(rs, 32);
      // P -> wave-private LDS (b64 writes, 2-way = free)
#pragma unroll
      for (int kt = 0; kt < 4; ++kt) {
        bf16x4 pv;
#pragma unroll
        for (int r = 0; r < 4; ++r) pv[r] = (__bf16)st[kt][r];
        *(bf16x4*)&pqw[lr * 72 + kt * 16 + quad * 4] = pv;
      }
      if (noresc) {
        l_i += rs;
      } else {
        const float alpha = exp2f(m_i - mnew);
        l_i = l_i * alpha + rs;
        m_i = mnew;
#pragma unroll
        for (int dt = 0; dt < 4; ++dt)
#pragma unroll
          for (int r = 0; r < 4; ++r) o_acc[dt][r] *= alpha;
      }

      // single LDS-only fence: P writes visible to own wave's ds_reads;
      // leaves the depth-2 global prefetch in flight.
      asm volatile("s_waitcnt lgkmcnt(0)" ::: "memory");
      __builtin_amdgcn_sched_barrier(0);

      // O^T += V^T * P^T (swizzled block addressing) from Vt[cur]
      __builtin_amdgcn_s_setprio(1);
#pragma unroll
      for (int ks = 0; ks < 2; ++ks) {
        bf16x8 av[4];
#pragma unroll
        for (int dt = 0; dt < 4; ++dt) {
          const int blk = ((ks << 2) + quad) ^ ((2 * dt + (lr >> 3)) & 3);
          av[dt] = *(const bf16x8*)&Vt[cur][(dt * 16 + lr) * 72 + (blk << 3)];
        }
        bf16x8 bp = *(const bf16x8*)&pqw[lr * 72 + ks * 32 + quad * 8];
#pragma unroll
        for (int dt = 0; dt < 4; ++dt) o_acc[dt] = MFMA16(av[dt], bp, o_acc[dt]);
      }
      __builtin_amdgcn_s_setprio(0);
    }

    __syncthreads();  // single barrier per tile: staging of t+1 visible,
                      // reads of buf[cur] complete before iter t+1 overwrites
  }

  // epilogue: O/l -> q-slice in place (one q-group per wave)
  {
    const float inv = 1.f / fmaxf(l_i, 1e-30f);
    const long obase = base + (long)qi * 3072 + h * 64 + quad * 4;
#pragma unroll
    for (int dt = 0; dt < 4; ++dt) {
      bf16x4 ov;
#pragma unroll
      for (int r = 0; r < 4; ++r) ov[r] = (__bf16)(o_acc[dt][r] * inv);
      *(bf16x4*)(qkv + obase + dt * 16) = ov;
    }
  }
}

extern "C" void kernel_launch(void* const* d_in, const int* in_sizes, int n_in,
                              void* d_out, int out_size, void* d_ws, size_t ws_size,
                              hipStream_t stream) {
  const float* x = (const float*)d_in[0];
  const float* w_qkv = (const float*)d_in[1];
  const float* w_o = (const float*)d_in[2];
  for (int i = 0; i < n_in; ++i) {
    if (in_sizes[i] == MTOT * DM) x = (const float*)d_in[i];
    else if (in_sizes[i] == 3 * DM * DM) w_qkv = (const float*)d_in[i];
    else if (in_sizes[i] == DM * DM) w_o = (const float*)d_in[i];
  }
  float* out = (float*)d_out;  // FP32 output per reference dtype

  const size_t qkvBytes = (size_t)MTOT * 3072 * 2;       // 24 MiB
  const size_t xbBytes = (size_t)MTOT * DM * 2;          // 8 MiB
  const size_t wqBytes = (size_t)3 * DM * DM * 2;        // 6 MiB
  const size_t woBytes = (size_t)DM * DM * 2;            // 2 MiB
  const size_t needFast = qkvBytes + xbBytes + wqBytes + woBytes;  // 40 MiB

  __bf16* qkv = (__bf16*)d_ws;

  if (ws_size >= needFast) {
    __bf16* xb = (__bf16*)((char*)d_ws + qkvBytes);
    __bf16* wqb = (__bf16*)((char*)d_ws + qkvBytes + xbBytes);
    __bf16* wob = (__bf16*)((char*)d_ws + qkvBytes + xbBytes + wqBytes);
    cvt_all<<<4096, 256, 0, stream>>>(x, w_qkv, w_o, xb, wqb, wob);
    gemm256<__bf16><<<dim3(3072 / 256, MTOT / 256), 512, 0, stream>>>(
        xb, wqb, qkv, MTOT, 3072, DM, DM, 1e4f);
    attn_fwd<<<dim3(16, NH, BATCH), 512, 0, stream>>>(qkv);
    gemm_bt64<float><<<dim3(DM / 128, MTOT / 64), 256, 0, stream>>>(
        qkv, wob, out, MTOT, DM, DM, 3072, 2e4f);
  } else if (ws_size >= qkvBytes) {
    gemm_nt<1, 1, __bf16><<<dim3(3072 / 128, MTOT / 128), 256, 0, stream>>>(
        x, w_qkv, qkv, MTOT, 3072, DM, DM, 1e4f);
    attn_fwd<<<dim3(16, NH, BATCH), 512, 0, stream>>>(qkv);
    gemm_nt<0, 1, float><<<dim3(DM / 128, MTOT / 128), 256, 0, stream>>>(
        qkv, w_o, out, MTOT, DM, DM, 3072, 2e4f);
  } else {
    sentinel_fill<<<256, 256, 0, stream>>>(out, out_size);
  }
}

// Round 11
// 209.382 us; speedup vs baseline: 1.1076x; 1.1076x over previous
//
#include <hip/hip_runtime.h>

constexpr int SEQ = 2048;
constexpr int DM = 1024;
constexpr int NH = 16;
constexpr int BATCH = 2;
constexpr int MTOT = BATCH * SEQ;   // 4096

typedef __bf16 bf16x8 __attribute__((ext_vector_type(8)));
typedef __bf16 bf16x4 __attribute__((ext_vector_type(4)));
typedef float f32x4 __attribute__((ext_vector_type(4)));

#define MFMA16(a, b, c) __builtin_amdgcn_mfma_f32_16x16x32_bf16((a), (b), (c), 0, 0, 0)

__device__ __forceinline__ void async_copy16(const void* g, void* l) {
  __builtin_amdgcn_global_load_lds((const __attribute__((address_space(1))) void*)g,
                                   (__attribute__((address_space(3))) void*)l, 16, 0, 0);
}

// T1 bijective XCD swizzle (R7): contiguous block chunks per XCD. nwg%8==0.
__device__ __forceinline__ void xcd_swizzle(int& bx, int& by) {
  const int gx = gridDim.x;
  const int nwg = gx * gridDim.y;
  const int bid = blockIdx.y * gx + blockIdx.x;
  const int cpx = nwg >> 3;
  const int v = (bid & 7) * cpx + (bid >> 3);
  by = v / gx;
  bx = v - by * gx;
}

__global__ void sentinel_fill(float* out, int n) {
  int i = blockIdx.x * blockDim.x + threadIdx.x;
  for (; i < n; i += gridDim.x * blockDim.x) out[i] = 0.25f;
}

// one-shot fp32 -> bf16 conversion of x, w_qkv, w_o
__global__ __launch_bounds__(256) void cvt_all(const float* __restrict__ x,
                                               const float* __restrict__ wq,
                                               const float* __restrict__ wo,
                                               __bf16* __restrict__ xb,
                                               __bf16* __restrict__ wqb,
                                               __bf16* __restrict__ wob) {
  const long i = (long)(blockIdx.x * 256 + threadIdx.x) * 8;
  const float* src;
  __bf16* dst;
  long off;
  if (i < 4194304) { src = x; dst = xb; off = i; }
  else if (i < 7340032) { src = wq; dst = wqb; off = i - 4194304; }
  else { src = wo; dst = wob; off = i - 7340032; }
  f32x4 lo = *(const f32x4*)(src + off);
  f32x4 hi = *(const f32x4*)(src + off + 4);
  bf16x8 r;
#pragma unroll
  for (int j = 0; j < 4; ++j) { r[j] = (__bf16)lo[j]; r[4 + j] = (__bf16)hi[j]; }
  *(bf16x8*)(dst + off) = r;
}

// FAST GEMM: C[M,N]=A[M,K]*B[N,K]^T, 128x128 tile, m97 fragment geometry.
// R8 counted-vmcnt 3-buffer pipeline + R7 XCD swizzle. RESTORED in R11 after
// the R10 256^2 experiment regressed (192-block grid left 25% of CUs idle;
// 128B-row-stride LDS -> 16-way bank conflict; 1 block/CU lost cross-block
// overlap). This 768-block 3-blocks/CU config is the verified best (~65us).
template <typename OutT>
__global__ __launch_bounds__(256) void gemm_bt(const __bf16* __restrict__ A,
                                               const __bf16* __restrict__ B,
                                               OutT* __restrict__ C,
                                               int M, int N, int K, int lda,
                                               float nanSig) {
  __shared__ alignas(16) __bf16 As[3][128 * 32];
  __shared__ alignas(16) __bf16 Bs[3][128 * 32];
  const int tid = threadIdx.x;
  const int lane = tid & 63;
  const int wave = tid >> 6;
  const int lr = lane & 15;
  const int quad = lane >> 4;
  const int wm = (wave >> 1) * 64;
  const int wn = (wave & 1) * 64;
  int bx, by;
  xcd_swizzle(bx, by);
  const int m0 = by * 128;
  const int n0 = bx * 128;

  const int ra = tid >> 2;
  const int ca = (tid & 3) * 8;
  const __bf16* gA0 = A + (long)(m0 + ra) * lda + ca;
  const __bf16* gA1 = A + (long)(m0 + 64 + ra) * lda + ca;
  const __bf16* gB0 = B + (long)(n0 + ra) * K + ca;
  const __bf16* gB1 = B + (long)(n0 + 64 + ra) * K + ca;

  f32x4 acc[4][4];
#pragma unroll
  for (int i = 0; i < 4; ++i)
#pragma unroll
    for (int j = 0; j < 4; ++j) acc[i][j] = (f32x4){0.f, 0.f, 0.f, 0.f};

  auto stage = [&](int bi, int k0) {
    async_copy16(gA0 + k0, &As[bi][wave * 512]);
    async_copy16(gA1 + k0, &As[bi][2048 + wave * 512]);
    async_copy16(gB0 + k0, &Bs[bi][wave * 512]);
    async_copy16(gB1 + k0, &Bs[bi][2048 + wave * 512]);
  };

  const int nt = K >> 5;
  stage(0, 0);
  if (nt > 1) stage(1, 32);

  int cur = 0;
  for (int t = 0; t < nt; ++t) {
    if (t + 1 < nt) {
      asm volatile("s_waitcnt vmcnt(4)" ::: "memory");
    } else {
      asm volatile("s_waitcnt vmcnt(0)" ::: "memory");
    }
    __builtin_amdgcn_sched_barrier(0);
    __builtin_amdgcn_s_barrier();  // stage(t) visible; buf[(t-1)%3] reads done
    if (t + 2 < nt) stage(cur == 0 ? 2 : cur - 1, (t + 2) * 32);  // (t+2)%3

    bf16x8 af[4], bfr[4];
#pragma unroll
    for (int i = 0; i < 4; ++i)
      af[i] = *(const bf16x8*)&As[cur][(wm + i * 16 + lr) * 32 + quad * 8];
#pragma unroll
    for (int j = 0; j < 4; ++j)
      bfr[j] = *(const bf16x8*)&Bs[cur][(wn + j * 16 + lr) * 32 + quad * 8];
    __builtin_amdgcn_s_setprio(1);
#pragma unroll
    for (int i = 0; i < 4; ++i)
#pragma unroll
      for (int j = 0; j < 4; ++j) acc[i][j] = MFMA16(af[i], bfr[j], acc[i][j]);
    __builtin_amdgcn_s_setprio(0);
    cur = (cur == 2) ? 0 : cur + 1;
  }

#pragma unroll
  for (int i = 0; i < 4; ++i) {
    const int row = m0 + wm + i * 16 + quad * 4;
#pragma unroll
    for (int j = 0; j < 4; ++j) {
      const int col = n0 + wn + j * 16 + lr;
#pragma unroll
      for (int r = 0; r < 4; ++r) {
        float v = acc[i][j][r];
        if (!(v == v)) v = nanSig;
        C[(long)(row + r) * N + col] = (OutT)v;
      }
    }
  }
}

// 64x128-tile variant for gemm2 (R7/R8, kept): 512 blocks = 2/CU,
// counted-vmcnt 3-buffer pipeline. LDS 36 KB.
template <typename OutT>
__global__ __launch_bounds__(256) void gemm_bt64(const __bf16* __restrict__ A,
                                                 const __bf16* __restrict__ B,
                                                 OutT* __restrict__ C,
                                                 int M, int N, int K, int lda,
                                                 float nanSig) {
  __shared__ alignas(16) __bf16 As[3][64 * 32];
  __shared__ alignas(16) __bf16 Bs[3][128 * 32];
  const int tid = threadIdx.x;
  const int lane = tid & 63;
  const int wave = tid >> 6;
  const int lr = lane & 15;
  const int quad = lane >> 4;
  const int wm = (wave >> 1) * 32;
  const int wn = (wave & 1) * 64;
  int bx, by;
  xcd_swizzle(bx, by);
  const int m0 = by * 64;
  const int n0 = bx * 128;

  const int ra = tid >> 2;          // 0..63
  const int ca = (tid & 3) * 8;
  const __bf16* gA0 = A + (long)(m0 + ra) * lda + ca;
  const __bf16* gB0 = B + (long)(n0 + ra) * K + ca;
  const __bf16* gB1 = B + (long)(n0 + 64 + ra) * K + ca;

  f32x4 acc[2][4];
#pragma unroll
  for (int i = 0; i < 2; ++i)
#pragma unroll
    for (int j = 0; j < 4; ++j) acc[i][j] = (f32x4){0.f, 0.f, 0.f, 0.f};

  auto stage = [&](int bi, int k0) {
    async_copy16(gA0 + k0, &As[bi][wave * 512]);
    async_copy16(gB0 + k0, &Bs[bi][wave * 512]);
    async_copy16(gB1 + k0, &Bs[bi][2048 + wave * 512]);
  };

  const int nt = K >> 5;
  stage(0, 0);
  if (nt > 1) stage(1, 32);

  int cur = 0;
  for (int t = 0; t < nt; ++t) {
    if (t + 1 < nt) {
      asm volatile("s_waitcnt vmcnt(3)" ::: "memory");
    } else {
      asm volatile("s_waitcnt vmcnt(0)" ::: "memory");
    }
    __builtin_amdgcn_sched_barrier(0);
    __builtin_amdgcn_s_barrier();
    if (t + 2 < nt) stage(cur == 0 ? 2 : cur - 1, (t + 2) * 32);

    bf16x8 af[2], bfr[4];
#pragma unroll
    for (int i = 0; i < 2; ++i)
      af[i] = *(const bf16x8*)&As[cur][(wm + i * 16 + lr) * 32 + quad * 8];
#pragma unroll
    for (int j = 0; j < 4; ++j)
      bfr[j] = *(const bf16x8*)&Bs[cur][(wn + j * 16 + lr) * 32 + quad * 8];
    __builtin_amdgcn_s_setprio(1);
#pragma unroll
    for (int i = 0; i < 2; ++i)
#pragma unroll
      for (int j = 0; j < 4; ++j) acc[i][j] = MFMA16(af[i], bfr[j], acc[i][j]);
    __builtin_amdgcn_s_setprio(0);
    cur = (cur == 2) ? 0 : cur + 1;
  }

#pragma unroll
  for (int i = 0; i < 2; ++i) {
    const int row = m0 + wm + i * 16 + quad * 4;
#pragma unroll
    for (int j = 0; j < 4; ++j) {
      const int col = n0 + wn + j * 16 + lr;
#pragma unroll
      for (int r = 0; r < 4; ++r) {
        float v = acc[i][j][r];
        if (!(v == v)) v = nanSig;
        C[(long)(row + r) * N + col] = (OutT)v;
      }
    }
  }
}

// SLOW fallback GEMM (inline fp32 cvt, verified R9).
template <int F32>
__device__ __forceinline__ bf16x8 load_cvt8(const void* base, long off) {
  if constexpr (F32) {
    const float* p = (const float*)base + off;
    f32x4 lo = *(const f32x4*)p;
    f32x4 hi = *(const f32x4*)(p + 4);
    bf16x8 r;
#pragma unroll
    for (int j = 0; j < 4; ++j) { r[j] = (__bf16)lo[j]; r[4 + j] = (__bf16)hi[j]; }
    return r;
  } else {
    return *(const bf16x8*)((const __bf16*)base + off);
  }
}

template <int AF32, int BF32, typename OutT>
__global__ __launch_bounds__(256) void gemm_nt(const void* __restrict__ Av,
                                               const void* __restrict__ Bv,
                                               OutT* __restrict__ C,
                                               int M, int N, int K, int lda,
                                               float nanSig) {
  __shared__ alignas(16) __bf16 As[128 * 32];
  __shared__ alignas(16) __bf16 Bs[128 * 32];
  const int tid = threadIdx.x;
  const int lane = tid & 63;
  const int wave = tid >> 6;
  const int lr = lane & 15;
  const int quad = lane >> 4;
  const int wm = (wave >> 1) * 64;
  const int wn = (wave & 1) * 64;
  const int m0 = blockIdx.y * 128;
  const int n0 = blockIdx.x * 128;

  const int r0 = tid >> 2;
  const int r1 = 64 + (tid >> 2);
  const int cc = (tid & 3) * 8;
  const long aBase0 = (long)(m0 + r0) * lda + cc;
  const long aBase1 = (long)(m0 + r1) * lda + cc;
  const long bBase0 = (long)(n0 + r0) * K + cc;
  const long bBase1 = (long)(n0 + r1) * K + cc;
  __bf16* lA0 = &As[r0 * 32 + cc];
  __bf16* lA1 = &As[r1 * 32 + cc];
  __bf16* lB0 = &Bs[r0 * 32 + cc];
  __bf16* lB1 = &Bs[r1 * 32 + cc];

  f32x4 acc[4][4];
#pragma unroll
  for (int i = 0; i < 4; ++i)
#pragma unroll
    for (int j = 0; j < 4; ++j) acc[i][j] = (f32x4){0.f, 0.f, 0.f, 0.f};

  for (int k0 = 0; k0 < K; k0 += 32) {
    bf16x8 va0 = load_cvt8<AF32>(Av, aBase0 + k0);
    bf16x8 va1 = load_cvt8<AF32>(Av, aBase1 + k0);
    bf16x8 vb0 = load_cvt8<BF32>(Bv, bBase0 + k0);
    bf16x8 vb1 = load_cvt8<BF32>(Bv, bBase1 + k0);
    __syncthreads();
    *(bf16x8*)lA0 = va0;
    *(bf16x8*)lA1 = va1;
    *(bf16x8*)lB0 = vb0;
    *(bf16x8*)lB1 = vb1;
    __syncthreads();
    bf16x8 af[4], bfr[4];
#pragma unroll
    for (int i = 0; i < 4; ++i) af[i] = *(const bf16x8*)&As[(wm + i * 16 + lr) * 32 + quad * 8];
#pragma unroll
    for (int j = 0; j < 4; ++j) bfr[j] = *(const bf16x8*)&Bs[(wn + j * 16 + lr) * 32 + quad * 8];
#pragma unroll
    for (int i = 0; i < 4; ++i)
#pragma unroll
      for (int j = 0; j < 4; ++j) acc[i][j] = MFMA16(af[i], bfr[j], acc[i][j]);
  }

#pragma unroll
  for (int i = 0; i < 4; ++i) {
    const int row = m0 + wm + i * 16 + quad * 4;
#pragma unroll
    for (int j = 0; j < 4; ++j) {
      const int col = n0 + wn + j * 16 + lr;
#pragma unroll
      for (int r = 0; r < 4; ++r) {
        float v = acc[i][j][r];
        if (!(v == v)) v = nanSig;
        C[(long)(row + r) * N + col] = (OutT)v;
      }
    }
  }
}

// Flash causal attention, S^T form. R9 QG-PER-WAVE SPLIT (kept, untouched —
// R9 confirmed attn is at its structural plateau: occupancy 19->31% with time
// flat, so the per-tile staging/barrier convoy is the floor). 512 threads;
// waves 0-3 own q-tile B, waves 4-7 own q-tile A. Grid 16x16x2 = 512 blocks.
__global__ __launch_bounds__(512, 4) void attn_fwd(__bf16* __restrict__ qkv) {
  const int pi = blockIdx.x;      // 0..15: pair id
  const int h = blockIdx.y;
  const int b = blockIdx.z;
  const int q0A = pi * 64;
  const int q0B = (31 - pi) * 64;
  const int tid = threadIdx.x;
  const int lane = tid & 63;
  const int wave = tid >> 6;      // 0..7
  const int grp = wave >> 2;      // 0: q-tile B (full range), 1: q-tile A
  const int q0X = grp ? q0A : q0B;
  const int lr = lane & 15;
  const int quad = lane >> 4;
  const int wq = (wave & 3) * 16;
  const int qi = q0X + wq + lr;

  __shared__ alignas(16) __bf16 Ks[2][64 * 72];  // K rows [kv][d], double-buffered
  __shared__ alignas(16) __bf16 Vt[2][64 * 72];  // V^T [d][kv^swz], double-buffered
  __shared__ alignas(16) __bf16 Pq[128 * 72];    // P [wave*16 + q][kv]

  __bf16* pqw = &Pq[wave * 16 * 72];
  const long base = (long)b * SEQ * 3072;

  // Q as B-operand fragments (one q-group per wave)
  bf16x8 b_q[2];
  {
    const long rowoff = base + (long)qi * 3072 + h * 64;
    b_q[0] = *(const bf16x8*)(qkv + rowoff + quad * 8);
    b_q[1] = *(const bf16x8*)(qkv + rowoff + 32 + quad * 8);
  }

  const float NEGS = -30000.f;
  const float SC = 0.18033688f;  // 0.125 * log2(e): softmax in exp2 domain
  float m_i = NEGS, l_i = 0.f;
  f32x4 o_acc[4];
#pragma unroll
  for (int dt = 0; dt < 4; ++dt) o_acc[dt] = (f32x4){0.f, 0.f, 0.f, 0.f};

  // staging thread geometry (512 stagers: 1 row each)
  const int r_ = tid >> 3;            // 0..63
  const int col_ = (tid & 7) * 8;     // 0..56
  const int l8 = tid & 7;
  const int sw = (l8 & 3) << 3;       // Vt swizzle amount for this thread's cols
  const bool oddr = (tid >> 3) & 1;
  const int jb = oddr ? 4 : 0;

  const int Tb = 32 - pi;             // B's full causal range in KV tiles, >= 17

  bf16x8 kreg, vreg;
  auto loadTile = [&](int t) {
    const long ro = base + ((long)t * 64 + r_) * 3072 + h * 64 + col_;
    kreg = *(const bf16x8*)(qkv + ro + 1024);
    vreg = *(const bf16x8*)(qkv + ro + 2048);
  };
  auto stageTile = [&](int bi) {
    __bf16* ks = &Ks[bi][0];
    __bf16* vt = &Vt[bi][0];
    // K row -> LDS (b128)
    *(bf16x8*)&ks[r_ * 72 + col_] = kreg;
    // V^T via pair-transpose + swizzle (b32 writes, 2-way banks = free)
    const int rr = (r_ & ~1) ^ sw;
    int vd[4], od[4];
    __builtin_memcpy(vd, &vreg, 16);
#pragma unroll
    for (int i = 0; i < 4; ++i) od[i] = __shfl_xor(vd[i], 8);
#pragma unroll
    for (int i = 0; i < 4; ++i) {
      const int j = jb + i;
      const int a = vd[j >> 1], bb = od[j >> 1];
      const int lo = oddr ? bb : a;
      const int hi = oddr ? a : bb;
      const int pair = (j & 1) ? (int)(((unsigned)lo >> 16) | (hi & 0xffff0000))
                               : (int)((lo & 0xffff) | (hi << 16));
      *(int*)&vt[(col_ + j) * 72 + rr] = pair;
    }
  };

  // prologue: stage tile 0 into buf0, issue loads for tile 1
  loadTile(0);
  stageTile(0);
  loadTile(1);  // Tb >= 17, always valid
  __syncthreads();

  for (int t = 0; t < Tb; ++t) {
    const int cur = t & 1;
    const int kv0 = t * 64;
    // wave-uniform: B-waves always active; A-waves while kv in causal range
    const bool act = (grp == 0) || (kv0 <= q0A + wq + 15);

    // S^T = K * Q^T from Ks[cur]
    f32x4 st[4];
#pragma unroll
    for (int kt = 0; kt < 4; ++kt) st[kt] = (f32x4){0.f, 0.f, 0.f, 0.f};
    if (act) {
      __builtin_amdgcn_s_setprio(1);
#pragma unroll
      for (int ks = 0; ks < 2; ++ks) {
        bf16x8 ak[4];
#pragma unroll
        for (int kt = 0; kt < 4; ++kt)
          ak[kt] = *(const bf16x8*)&Ks[cur][(kt * 16 + lr) * 72 + ks * 32 + quad * 8];
#pragma unroll
        for (int kt = 0; kt < 4; ++kt) st[kt] = MFMA16(ak[kt], b_q[ks], st[kt]);
      }
      __builtin_amdgcn_s_setprio(0);
    }

    // stage tile t+1 into the other buffer (overlaps with softmax below),
    // then issue global loads for tile t+2 (consumed by next iter's stage).
    if (t + 1 < Tb) stageTile(cur ^ 1);
    if (t + 2 < Tb) loadTile(t + 2);

    if (act) {
      // scale (exp2 domain) + causal mask
      if (kv0 + 64 <= q0X + wq) {
#pragma unroll
        for (int kt = 0; kt < 4; ++kt)
#pragma unroll
          for (int r = 0; r < 4; ++r) st[kt][r] *= SC;
      } else {
#pragma unroll
        for (int kt = 0; kt < 4; ++kt) {
          const int d0 = kv0 + kt * 16 + quad * 4 - qi;
#pragma unroll
          for (int r = 0; r < 4; ++r)
            st[kt][r] = (d0 + r <= 0) ? st[kt][r] * SC : NEGS;
        }
      }
      // online softmax (in-lane over 16 kv + 2 shfl)
      float mx = st[0][0];
#pragma unroll
      for (int kt = 0; kt < 4; ++kt)
#pragma unroll
        for (int r = 0; r < 4; ++r) mx = fmaxf(mx, st[kt][r]);
      mx = fmaxf(mx, __shfl_xor(mx, 16));
      mx = fmaxf(mx, __shfl_xor(mx, 32));
      // T13 defer-rescale: keep old max while growth <= 8 (P bounded by 2^8)
      const bool noresc = __all(mx - m_i <= 8.f);
      const float mnew = noresc ? m_i : fmaxf(m_i, mx);
      float rs = 0.f;
#pragma unroll
      for (int kt = 0; kt < 4; ++kt)
#pragma unroll
        for (int r = 0; r < 4; ++r) {
          const float p = exp2f(st[kt][r] - mnew);
          st[kt][r] = p;
          rs += p;
        }
      rs += __shfl_xor(rs, 16);
      rs += __shfl_xor(rs, 32);
      // P -> wave-private LDS (b64 writes, 2-way = free)
#pragma unroll
      for (int kt = 0; kt < 4; ++kt) {
        bf16x4 pv;
#pragma unroll
        for (int r = 0; r < 4; ++r) pv[r] = (__bf16)st[kt][r];
        *(bf16x4*)&pqw[lr * 72 + kt * 16 + quad * 4] = pv;
      }
      if (noresc) {
        l_i += rs;
      } else {
        const float alpha = exp2f(m_i - mnew);
        l_i = l_i * alpha + rs;
        m_i = mnew;
#pragma unroll
        for (int dt = 0; dt < 4; ++dt)
#pragma unroll
          for (int r = 0; r < 4; ++r) o_acc[dt][r] *= alpha;
      }

      // single LDS-only fence: P writes visible to own wave's ds_reads;
      // leaves the depth-2 global prefetch in flight.
      asm volatile("s_waitcnt lgkmcnt(0)" ::: "memory");
      __builtin_amdgcn_sched_barrier(0);

      // O^T += V^T * P^T (swizzled block addressing) from Vt[cur]
      __builtin_amdgcn_s_setprio(1);
#pragma unroll
      for (int ks = 0; ks < 2; ++ks) {
        bf16x8 av[4];
#pragma unroll
        for (int dt = 0; dt < 4; ++dt) {
          const int blk = ((ks << 2) + quad) ^ ((2 * dt + (lr >> 3)) & 3);
          av[dt] = *(const bf16x8*)&Vt[cur][(dt * 16 + lr) * 72 + (blk << 3)];
        }
        bf16x8 bp = *(const bf16x8*)&pqw[lr * 72 + ks * 32 + quad * 8];
#pragma unroll
        for (int dt = 0; dt < 4; ++dt) o_acc[dt] = MFMA16(av[dt], bp, o_acc[dt]);
      }
      __builtin_amdgcn_s_setprio(0);
    }

    __syncthreads();  // single barrier per tile: staging of t+1 visible,
                      // reads of buf[cur] complete before iter t+1 overwrites
  }

  // epilogue: O/l -> q-slice in place (one q-group per wave)
  {
    const float inv = 1.f / fmaxf(l_i, 1e-30f);
    const long obase = base + (long)qi * 3072 + h * 64 + quad * 4;
#pragma unroll
    for (int dt = 0; dt < 4; ++dt) {
      bf16x4 ov;
#pragma unroll
      for (int r = 0; r < 4; ++r) ov[r] = (__bf16)(o_acc[dt][r] * inv);
      *(bf16x4*)(qkv + obase + dt * 16) = ov;
    }
  }
}

extern "C" void kernel_launch(void* const* d_in, const int* in_sizes, int n_in,
                              void* d_out, int out_size, void* d_ws, size_t ws_size,
                              hipStream_t stream) {
  const float* x = (const float*)d_in[0];
  const float* w_qkv = (const float*)d_in[1];
  const float* w_o = (const float*)d_in[2];
  for (int i = 0; i < n_in; ++i) {
    if (in_sizes[i] == MTOT * DM) x = (const float*)d_in[i];
    else if (in_sizes[i] == 3 * DM * DM) w_qkv = (const float*)d_in[i];
    else if (in_sizes[i] == DM * DM) w_o = (const float*)d_in[i];
  }
  float* out = (float*)d_out;  // FP32 output per reference dtype

  const size_t qkvBytes = (size_t)MTOT * 3072 * 2;       // 24 MiB
  const size_t xbBytes = (size_t)MTOT * DM * 2;          // 8 MiB
  const size_t wqBytes = (size_t)3 * DM * DM * 2;        // 6 MiB
  const size_t woBytes = (size_t)DM * DM * 2;            // 2 MiB
  const size_t needFast = qkvBytes + xbBytes + wqBytes + woBytes;  // 40 MiB

  __bf16* qkv = (__bf16*)d_ws;

  if (ws_size >= needFast) {
    __bf16* xb = (__bf16*)((char*)d_ws + qkvBytes);
    __bf16* wqb = (__bf16*)((char*)d_ws + qkvBytes + xbBytes);
    __bf16* wob = (__bf16*)((char*)d_ws + qkvBytes + xbBytes + wqBytes);
    cvt_all<<<4096, 256, 0, stream>>>(x, w_qkv, w_o, xb, wqb, wob);
    gemm_bt<__bf16><<<dim3(3072 / 128, MTOT / 128), 256, 0, stream>>>(
        xb, wqb, qkv, MTOT, 3072, DM, DM, 1e4f);
    attn_fwd<<<dim3(16, NH, BATCH), 512, 0, stream>>>(qkv);
    gemm_bt64<float><<<dim3(DM / 128, MTOT / 64), 256, 0, stream>>>(
        qkv, wob, out, MTOT, DM, DM, 3072, 2e4f);
  } else if (ws_size >= qkvBytes) {
    gemm_nt<1, 1, __bf16><<<dim3(3072 / 128, MTOT / 128), 256, 0, stream>>>(
        x, w_qkv, qkv, MTOT, 3072, DM, DM, 1e4f);
    attn_fwd<<<dim3(16, NH, BATCH), 512, 0, stream>>>(qkv);
    gemm_nt<0, 1, float><<<dim3(DM / 128, MTOT / 128), 256, 0, stream>>>(
        qkv, w_o, out, MTOT, DM, DM, 3072, 2e4f);
  } else {
    sentinel_fill<<<256, 256, 0, stream>>>(out, out_size);
  }
}

// Round 12
// 208.450 us; speedup vs baseline: 1.1125x; 1.0045x over previous
//
#include <hip/hip_runtime.h>

constexpr int SEQ = 2048;
constexpr int DM = 1024;
constexpr int NH = 16;
constexpr int BATCH = 2;
constexpr int MTOT = BATCH * SEQ;   // 4096

typedef __bf16 bf16x8 __attribute__((ext_vector_type(8)));
typedef __bf16 bf16x4 __attribute__((ext_vector_type(4)));
typedef float f32x4 __attribute__((ext_vector_type(4)));

#define MFMA16(a, b, c) __builtin_amdgcn_mfma_f32_16x16x32_bf16((a), (b), (c), 0, 0, 0)

__device__ __forceinline__ void async_copy16(const void* g, void* l) {
  __builtin_amdgcn_global_load_lds((const __attribute__((address_space(1))) void*)g,
                                   (__attribute__((address_space(3))) void*)l, 16, 0, 0);
}

// T1 bijective XCD swizzle (R7): contiguous block chunks per XCD. nwg%8==0.
__device__ __forceinline__ void xcd_swizzle(int& bx, int& by) {
  const int gx = gridDim.x;
  const int nwg = gx * gridDim.y;
  const int bid = blockIdx.y * gx + blockIdx.x;
  const int cpx = nwg >> 3;
  const int v = (bid & 7) * cpx + (bid >> 3);
  by = v / gx;
  bx = v - by * gx;
}

__global__ void sentinel_fill(float* out, int n) {
  int i = blockIdx.x * blockDim.x + threadIdx.x;
  for (; i < n; i += gridDim.x * blockDim.x) out[i] = 0.25f;
}

// one-shot fp32 -> bf16 conversion of x, w_qkv, w_o
__global__ __launch_bounds__(256) void cvt_all(const float* __restrict__ x,
                                               const float* __restrict__ wq,
                                               const float* __restrict__ wo,
                                               __bf16* __restrict__ xb,
                                               __bf16* __restrict__ wqb,
                                               __bf16* __restrict__ wob) {
  const long i = (long)(blockIdx.x * 256 + threadIdx.x) * 8;
  const float* src;
  __bf16* dst;
  long off;
  if (i < 4194304) { src = x; dst = xb; off = i; }
  else if (i < 7340032) { src = wq; dst = wqb; off = i - 4194304; }
  else { src = wo; dst = wob; off = i - 7340032; }
  f32x4 lo = *(const f32x4*)(src + off);
  f32x4 hi = *(const f32x4*)(src + off + 4);
  bf16x8 r;
#pragma unroll
  for (int j = 0; j < 4; ++j) { r[j] = (__bf16)lo[j]; r[4 + j] = (__bf16)hi[j]; }
  *(bf16x8*)(dst + off) = r;
}

// FAST GEMM: C[M,N]=A[M,K]*B[N,K]^T, 128x128 tile, m97 fragment geometry.
// R8 counted-vmcnt 3-buffer pipeline + R7 XCD swizzle (verified best, kept).
template <typename OutT>
__global__ __launch_bounds__(256) void gemm_bt(const __bf16* __restrict__ A,
                                               const __bf16* __restrict__ B,
                                               OutT* __restrict__ C,
                                               int M, int N, int K, int lda,
                                               float nanSig) {
  __shared__ alignas(16) __bf16 As[3][128 * 32];
  __shared__ alignas(16) __bf16 Bs[3][128 * 32];
  const int tid = threadIdx.x;
  const int lane = tid & 63;
  const int wave = tid >> 6;
  const int lr = lane & 15;
  const int quad = lane >> 4;
  const int wm = (wave >> 1) * 64;
  const int wn = (wave & 1) * 64;
  int bx, by;
  xcd_swizzle(bx, by);
  const int m0 = by * 128;
  const int n0 = bx * 128;

  const int ra = tid >> 2;
  const int ca = (tid & 3) * 8;
  const __bf16* gA0 = A + (long)(m0 + ra) * lda + ca;
  const __bf16* gA1 = A + (long)(m0 + 64 + ra) * lda + ca;
  const __bf16* gB0 = B + (long)(n0 + ra) * K + ca;
  const __bf16* gB1 = B + (long)(n0 + 64 + ra) * K + ca;

  f32x4 acc[4][4];
#pragma unroll
  for (int i = 0; i < 4; ++i)
#pragma unroll
    for (int j = 0; j < 4; ++j) acc[i][j] = (f32x4){0.f, 0.f, 0.f, 0.f};

  auto stage = [&](int bi, int k0) {
    async_copy16(gA0 + k0, &As[bi][wave * 512]);
    async_copy16(gA1 + k0, &As[bi][2048 + wave * 512]);
    async_copy16(gB0 + k0, &Bs[bi][wave * 512]);
    async_copy16(gB1 + k0, &Bs[bi][2048 + wave * 512]);
  };

  const int nt = K >> 5;
  stage(0, 0);
  if (nt > 1) stage(1, 32);

  int cur = 0;
  for (int t = 0; t < nt; ++t) {
    if (t + 1 < nt) {
      asm volatile("s_waitcnt vmcnt(4)" ::: "memory");
    } else {
      asm volatile("s_waitcnt vmcnt(0)" ::: "memory");
    }
    __builtin_amdgcn_sched_barrier(0);
    __builtin_amdgcn_s_barrier();  // stage(t) visible; buf[(t-1)%3] reads done
    if (t + 2 < nt) stage(cur == 0 ? 2 : cur - 1, (t + 2) * 32);  // (t+2)%3

    bf16x8 af[4], bfr[4];
#pragma unroll
    for (int i = 0; i < 4; ++i)
      af[i] = *(const bf16x8*)&As[cur][(wm + i * 16 + lr) * 32 + quad * 8];
#pragma unroll
    for (int j = 0; j < 4; ++j)
      bfr[j] = *(const bf16x8*)&Bs[cur][(wn + j * 16 + lr) * 32 + quad * 8];
    __builtin_amdgcn_s_setprio(1);
#pragma unroll
    for (int i = 0; i < 4; ++i)
#pragma unroll
      for (int j = 0; j < 4; ++j) acc[i][j] = MFMA16(af[i], bfr[j], acc[i][j]);
    __builtin_amdgcn_s_setprio(0);
    cur = (cur == 2) ? 0 : cur + 1;
  }

#pragma unroll
  for (int i = 0; i < 4; ++i) {
    const int row = m0 + wm + i * 16 + quad * 4;
#pragma unroll
    for (int j = 0; j < 4; ++j) {
      const int col = n0 + wn + j * 16 + lr;
#pragma unroll
      for (int r = 0; r < 4; ++r) {
        float v = acc[i][j][r];
        if (!(v == v)) v = nanSig;
        C[(long)(row + r) * N + col] = (OutT)v;
      }
    }
  }
}

// 64x128-tile variant for gemm2 (R7/R8, kept): 512 blocks = 2/CU,
// counted-vmcnt 3-buffer pipeline. LDS 36 KB.
template <typename OutT>
__global__ __launch_bounds__(256) void gemm_bt64(const __bf16* __restrict__ A,
                                                 const __bf16* __restrict__ B,
                                                 OutT* __restrict__ C,
                                                 int M, int N, int K, int lda,
                                                 float nanSig) {
  __shared__ alignas(16) __bf16 As[3][64 * 32];
  __shared__ alignas(16) __bf16 Bs[3][128 * 32];
  const int tid = threadIdx.x;
  const int lane = tid & 63;
  const int wave = tid >> 6;
  const int lr = lane & 15;
  const int quad = lane >> 4;
  const int wm = (wave >> 1) * 32;
  const int wn = (wave & 1) * 64;
  int bx, by;
  xcd_swizzle(bx, by);
  const int m0 = by * 64;
  const int n0 = bx * 128;

  const int ra = tid >> 2;          // 0..63
  const int ca = (tid & 3) * 8;
  const __bf16* gA0 = A + (long)(m0 + ra) * lda + ca;
  const __bf16* gB0 = B + (long)(n0 + ra) * K + ca;
  const __bf16* gB1 = B + (long)(n0 + 64 + ra) * K + ca;

  f32x4 acc[2][4];
#pragma unroll
  for (int i = 0; i < 2; ++i)
#pragma unroll
    for (int j = 0; j < 4; ++j) acc[i][j] = (f32x4){0.f, 0.f, 0.f, 0.f};

  auto stage = [&](int bi, int k0) {
    async_copy16(gA0 + k0, &As[bi][wave * 512]);
    async_copy16(gB0 + k0, &Bs[bi][wave * 512]);
    async_copy16(gB1 + k0, &Bs[bi][2048 + wave * 512]);
  };

  const int nt = K >> 5;
  stage(0, 0);
  if (nt > 1) stage(1, 32);

  int cur = 0;
  for (int t = 0; t < nt; ++t) {
    if (t + 1 < nt) {
      asm volatile("s_waitcnt vmcnt(3)" ::: "memory");
    } else {
      asm volatile("s_waitcnt vmcnt(0)" ::: "memory");
    }
    __builtin_amdgcn_sched_barrier(0);
    __builtin_amdgcn_s_barrier();
    if (t + 2 < nt) stage(cur == 0 ? 2 : cur - 1, (t + 2) * 32);

    bf16x8 af[2], bfr[4];
#pragma unroll
    for (int i = 0; i < 2; ++i)
      af[i] = *(const bf16x8*)&As[cur][(wm + i * 16 + lr) * 32 + quad * 8];
#pragma unroll
    for (int j = 0; j < 4; ++j)
      bfr[j] = *(const bf16x8*)&Bs[cur][(wn + j * 16 + lr) * 32 + quad * 8];
    __builtin_amdgcn_s_setprio(1);
#pragma unroll
    for (int i = 0; i < 2; ++i)
#pragma unroll
      for (int j = 0; j < 4; ++j) acc[i][j] = MFMA16(af[i], bfr[j], acc[i][j]);
    __builtin_amdgcn_s_setprio(0);
    cur = (cur == 2) ? 0 : cur + 1;
  }

#pragma unroll
  for (int i = 0; i < 2; ++i) {
    const int row = m0 + wm + i * 16 + quad * 4;
#pragma unroll
    for (int j = 0; j < 4; ++j) {
      const int col = n0 + wn + j * 16 + lr;
#pragma unroll
      for (int r = 0; r < 4; ++r) {
        float v = acc[i][j][r];
        if (!(v == v)) v = nanSig;
        C[(long)(row + r) * N + col] = (OutT)v;
      }
    }
  }
}

// SLOW fallback GEMM (inline fp32 cvt, verified R9).
template <int F32>
__device__ __forceinline__ bf16x8 load_cvt8(const void* base, long off) {
  if constexpr (F32) {
    const float* p = (const float*)base + off;
    f32x4 lo = *(const f32x4*)p;
    f32x4 hi = *(const f32x4*)(p + 4);
    bf16x8 r;
#pragma unroll
    for (int j = 0; j < 4; ++j) { r[j] = (__bf16)lo[j]; r[4 + j] = (__bf16)hi[j]; }
    return r;
  } else {
    return *(const bf16x8*)((const __bf16*)base + off);
  }
}

template <int AF32, int BF32, typename OutT>
__global__ __launch_bounds__(256) void gemm_nt(const void* __restrict__ Av,
                                               const void* __restrict__ Bv,
                                               OutT* __restrict__ C,
                                               int M, int N, int K, int lda,
                                               float nanSig) {
  __shared__ alignas(16) __bf16 As[128 * 32];
  __shared__ alignas(16) __bf16 Bs[128 * 32];
  const int tid = threadIdx.x;
  const int lane = tid & 63;
  const int wave = tid >> 6;
  const int lr = lane & 15;
  const int quad = lane >> 4;
  const int wm = (wave >> 1) * 64;
  const int wn = (wave & 1) * 64;
  const int m0 = blockIdx.y * 128;
  const int n0 = blockIdx.x * 128;

  const int r0 = tid >> 2;
  const int r1 = 64 + (tid >> 2);
  const int cc = (tid & 3) * 8;
  const long aBase0 = (long)(m0 + r0) * lda + cc;
  const long aBase1 = (long)(m0 + r1) * lda + cc;
  const long bBase0 = (long)(n0 + r0) * K + cc;
  const long bBase1 = (long)(n0 + r1) * K + cc;
  __bf16* lA0 = &As[r0 * 32 + cc];
  __bf16* lA1 = &As[r1 * 32 + cc];
  __bf16* lB0 = &Bs[r0 * 32 + cc];
  __bf16* lB1 = &Bs[r1 * 32 + cc];

  f32x4 acc[4][4];
#pragma unroll
  for (int i = 0; i < 4; ++i)
#pragma unroll
    for (int j = 0; j < 4; ++j) acc[i][j] = (f32x4){0.f, 0.f, 0.f, 0.f};

  for (int k0 = 0; k0 < K; k0 += 32) {
    bf16x8 va0 = load_cvt8<AF32>(Av, aBase0 + k0);
    bf16x8 va1 = load_cvt8<AF32>(Av, aBase1 + k0);
    bf16x8 vb0 = load_cvt8<BF32>(Bv, bBase0 + k0);
    bf16x8 vb1 = load_cvt8<BF32>(Bv, bBase1 + k0);
    __syncthreads();
    *(bf16x8*)lA0 = va0;
    *(bf16x8*)lA1 = va1;
    *(bf16x8*)lB0 = vb0;
    *(bf16x8*)lB1 = vb1;
    __syncthreads();
    bf16x8 af[4], bfr[4];
#pragma unroll
    for (int i = 0; i < 4; ++i) af[i] = *(const bf16x8*)&As[(wm + i * 16 + lr) * 32 + quad * 8];
#pragma unroll
    for (int j = 0; j < 4; ++j) bfr[j] = *(const bf16x8*)&Bs[(wn + j * 16 + lr) * 32 + quad * 8];
#pragma unroll
    for (int i = 0; i < 4; ++i)
#pragma unroll
      for (int j = 0; j < 4; ++j) acc[i][j] = MFMA16(af[i], bfr[j], acc[i][j]);
  }

#pragma unroll
  for (int i = 0; i < 4; ++i) {
    const int row = m0 + wm + i * 16 + quad * 4;
#pragma unroll
    for (int j = 0; j < 4; ++j) {
      const int col = n0 + wn + j * 16 + lr;
#pragma unroll
      for (int r = 0; r < 4; ++r) {
        float v = acc[i][j][r];
        if (!(v == v)) v = nanSig;
        C[(long)(row + r) * N + col] = (OutT)v;
      }
    }
  }
}

// Flash causal attention, S^T form. R9 QG-PER-WAVE SPLIT. R12: softmax VALU
// trim — running max m_i tracked in RAW score domain; mask is select-only
// (no mul); p = exp2(fma(st, SC, -m*SC)) folds the scale into the exp
// argument (eliminates 16 mul/tile/wave); pairwise max tree halves the
// fmax dep chain. Defer-rescale threshold 8/SC ~= 44 raw. Numerically
// identical up to FMA rounding.
__global__ __launch_bounds__(512, 4) void attn_fwd(__bf16* __restrict__ qkv) {
  const int pi = blockIdx.x;      // 0..15: pair id
  const int h = blockIdx.y;
  const int b = blockIdx.z;
  const int q0A = pi * 64;
  const int q0B = (31 - pi) * 64;
  const int tid = threadIdx.x;
  const int lane = tid & 63;
  const int wave = tid >> 6;      // 0..7
  const int grp = wave >> 2;      // 0: q-tile B (full range), 1: q-tile A
  const int q0X = grp ? q0A : q0B;
  const int lr = lane & 15;
  const int quad = lane >> 4;
  const int wq = (wave & 3) * 16;
  const int qi = q0X + wq + lr;

  __shared__ alignas(16) __bf16 Ks[2][64 * 72];  // K rows [kv][d], double-buffered
  __shared__ alignas(16) __bf16 Vt[2][64 * 72];  // V^T [d][kv^swz], double-buffered
  __shared__ alignas(16) __bf16 Pq[128 * 72];    // P [wave*16 + q][kv]

  __bf16* pqw = &Pq[wave * 16 * 72];
  const long base = (long)b * SEQ * 3072;

  // Q as B-operand fragments (one q-group per wave)
  bf16x8 b_q[2];
  {
    const long rowoff = base + (long)qi * 3072 + h * 64;
    b_q[0] = *(const bf16x8*)(qkv + rowoff + quad * 8);
    b_q[1] = *(const bf16x8*)(qkv + rowoff + 32 + quad * 8);
  }

  const float NEGS = -30000.f;       // raw-domain mask value
  const float SC = 0.18033688f;      // 0.125 * log2(e)
  float m_i = NEGS, l_i = 0.f;       // m_i in RAW score domain (R12)
  f32x4 o_acc[4];
#pragma unroll
  for (int dt = 0; dt < 4; ++dt) o_acc[dt] = (f32x4){0.f, 0.f, 0.f, 0.f};

  // staging thread geometry (512 stagers: 1 row each)
  const int r_ = tid >> 3;            // 0..63
  const int col_ = (tid & 7) * 8;     // 0..56
  const int l8 = tid & 7;
  const int sw = (l8 & 3) << 3;       // Vt swizzle amount for this thread's cols
  const bool oddr = (tid >> 3) & 1;
  const int jb = oddr ? 4 : 0;

  const int Tb = 32 - pi;             // B's full causal range in KV tiles, >= 17

  bf16x8 kreg, vreg;
  auto loadTile = [&](int t) {
    const long ro = base + ((long)t * 64 + r_) * 3072 + h * 64 + col_;
    kreg = *(const bf16x8*)(qkv + ro + 1024);
    vreg = *(const bf16x8*)(qkv + ro + 2048);
  };
  auto stageTile = [&](int bi) {
    __bf16* ks = &Ks[bi][0];
    __bf16* vt = &Vt[bi][0];
    // K row -> LDS (b128)
    *(bf16x8*)&ks[r_ * 72 + col_] = kreg;
    // V^T via pair-transpose + swizzle (b32 writes, 2-way banks = free)
    const int rr = (r_ & ~1) ^ sw;
    int vd[4], od[4];
    __builtin_memcpy(vd, &vreg, 16);
#pragma unroll
    for (int i = 0; i < 4; ++i) od[i] = __shfl_xor(vd[i], 8);
#pragma unroll
    for (int i = 0; i < 4; ++i) {
      const int j = jb + i;
      const int a = vd[j >> 1], bb = od[j >> 1];
      const int lo = oddr ? bb : a;
      const int hi = oddr ? a : bb;
      const int pair = (j & 1) ? (int)(((unsigned)lo >> 16) | (hi & 0xffff0000))
                               : (int)((lo & 0xffff) | (hi << 16));
      *(int*)&vt[(col_ + j) * 72 + rr] = pair;
    }
  };

  // prologue: stage tile 0 into buf0, issue loads for tile 1
  loadTile(0);
  stageTile(0);
  loadTile(1);  // Tb >= 17, always valid
  __syncthreads();

  for (int t = 0; t < Tb; ++t) {
    const int cur = t & 1;
    const int kv0 = t * 64;
    // wave-uniform: B-waves always active; A-waves while kv in causal range
    const bool act = (grp == 0) || (kv0 <= q0A + wq + 15);

    // S^T = K * Q^T from Ks[cur]
    f32x4 st[4];
#pragma unroll
    for (int kt = 0; kt < 4; ++kt) st[kt] = (f32x4){0.f, 0.f, 0.f, 0.f};
    if (act) {
      __builtin_amdgcn_s_setprio(1);
#pragma unroll
      for (int ks = 0; ks < 2; ++ks) {
        bf16x8 ak[4];
#pragma unroll
        for (int kt = 0; kt < 4; ++kt)
          ak[kt] = *(const bf16x8*)&Ks[cur][(kt * 16 + lr) * 72 + ks * 32 + quad * 8];
#pragma unroll
        for (int kt = 0; kt < 4; ++kt) st[kt] = MFMA16(ak[kt], b_q[ks], st[kt]);
      }
      __builtin_amdgcn_s_setprio(0);
    }

    // stage tile t+1 into the other buffer (overlaps with softmax below),
    // then issue global loads for tile t+2 (consumed by next iter's stage).
    if (t + 1 < Tb) stageTile(cur ^ 1);
    if (t + 2 < Tb) loadTile(t + 2);

    if (act) {
      // causal mask: select-only, raw domain (no scale mul — R12)
      if (kv0 + 64 > q0X + wq) {
#pragma unroll
        for (int kt = 0; kt < 4; ++kt) {
          const int d0 = kv0 + kt * 16 + quad * 4 - qi;
#pragma unroll
          for (int r = 0; r < 4; ++r)
            st[kt][r] = (d0 + r <= 0) ? st[kt][r] : NEGS;
        }
      }
      // max reduce: pairwise tree (halved dep chain) + 2 shfl
      float t0 = fmaxf(fmaxf(st[0][0], st[0][1]), fmaxf(st[0][2], st[0][3]));
      float t1 = fmaxf(fmaxf(st[1][0], st[1][1]), fmaxf(st[1][2], st[1][3]));
      float t2 = fmaxf(fmaxf(st[2][0], st[2][1]), fmaxf(st[2][2], st[2][3]));
      float t3 = fmaxf(fmaxf(st[3][0], st[3][1]), fmaxf(st[3][2], st[3][3]));
      float mx = fmaxf(fmaxf(t0, t1), fmaxf(t2, t3));
      mx = fmaxf(mx, __shfl_xor(mx, 16));
      mx = fmaxf(mx, __shfl_xor(mx, 32));
      // T13 defer-rescale: raw-domain threshold 8/SC ~= 44.36 -> 44
      const bool noresc = __all(mx - m_i <= 44.f);
      const float mnew = noresc ? m_i : fmaxf(m_i, mx);
      const float msc = mnew * SC;
      float rs = 0.f;
#pragma unroll
      for (int kt = 0; kt < 4; ++kt)
#pragma unroll
        for (int r = 0; r < 4; ++r) {
          const float p = exp2f(fmaf(st[kt][r], SC, -msc));
          st[kt][r] = p;
          rs += p;
        }
      rs += __shfl_xor(rs, 16);
      rs += __shfl_xor(rs, 32);
      // P -> wave-private LDS (b64 writes, 2-way = free)
#pragma unroll
      for (int kt = 0; kt < 4; ++kt) {
        bf16x4 pv;
#pragma unroll
        for (int r = 0; r < 4; ++r) pv[r] = (__bf16)st[kt][r];
        *(bf16x4*)&pqw[lr * 72 + kt * 16 + quad * 4] = pv;
      }
      if (noresc) {
        l_i += rs;
      } else {
        const float alpha = exp2f((m_i - mnew) * SC);
        l_i = l_i * alpha + rs;
        m_i = mnew;
#pragma unroll
        for (int dt = 0; dt < 4; ++dt)
#pragma unroll
          for (int r = 0; r < 4; ++r) o_acc[dt][r] *= alpha;
      }

      // single LDS-only fence: P writes visible to own wave's ds_reads;
      // leaves the depth-2 global prefetch in flight.
      asm volatile("s_waitcnt lgkmcnt(0)" ::: "memory");
      __builtin_amdgcn_sched_barrier(0);

      // O^T += V^T * P^T (swizzled block addressing) from Vt[cur]
      __builtin_amdgcn_s_setprio(1);
#pragma unroll
      for (int ks = 0; ks < 2; ++ks) {
        bf16x8 av[4];
#pragma unroll
        for (int dt = 0; dt < 4; ++dt) {
          const int blk = ((ks << 2) + quad) ^ ((2 * dt + (lr >> 3)) & 3);
          av[dt] = *(const bf16x8*)&Vt[cur][(dt * 16 + lr) * 72 + (blk << 3)];
        }
        bf16x8 bp = *(const bf16x8*)&pqw[lr * 72 + ks * 32 + quad * 8];
#pragma unroll
        for (int dt = 0; dt < 4; ++dt) o_acc[dt] = MFMA16(av[dt], bp, o_acc[dt]);
      }
      __builtin_amdgcn_s_setprio(0);
    }

    __syncthreads();  // single barrier per tile: staging of t+1 visible,
                      // reads of buf[cur] complete before iter t+1 overwrites
  }

  // epilogue: O/l -> q-slice in place (one q-group per wave)
  {
    const float inv = 1.f / fmaxf(l_i, 1e-30f);
    const long obase = base + (long)qi * 3072 + h * 64 + quad * 4;
#pragma unroll
    for (int dt = 0; dt < 4; ++dt) {
      bf16x4 ov;
#pragma unroll
      for (int r = 0; r < 4; ++r) ov[r] = (__bf16)(o_acc[dt][r] * inv);
      *(bf16x4*)(qkv + obase + dt * 16) = ov;
    }
  }
}

extern "C" void kernel_launch(void* const* d_in, const int* in_sizes, int n_in,
                              void* d_out, int out_size, void* d_ws, size_t ws_size,
                              hipStream_t stream) {
  const float* x = (const float*)d_in[0];
  const float* w_qkv = (const float*)d_in[1];
  const float* w_o = (const float*)d_in[2];
  for (int i = 0; i < n_in; ++i) {
    if (in_sizes[i] == MTOT * DM) x = (const float*)d_in[i];
    else if (in_sizes[i] == 3 * DM * DM) w_qkv = (const float*)d_in[i];
    else if (in_sizes[i] == DM * DM) w_o = (const float*)d_in[i];
  }
  float* out = (float*)d_out;  // FP32 output per reference dtype

  const size_t qkvBytes = (size_t)MTOT * 3072 * 2;       // 24 MiB
  const size_t xbBytes = (size_t)MTOT * DM * 2;          // 8 MiB
  const size_t wqBytes = (size_t)3 * DM * DM * 2;        // 6 MiB
  const size_t woBytes = (size_t)DM * DM * 2;            // 2 MiB
  const size_t needFast = qkvBytes + xbBytes + wqBytes + woBytes;  // 40 MiB

  __bf16* qkv = (__bf16*)d_ws;

  if (ws_size >= needFast) {
    __bf16* xb = (__bf16*)((char*)d_ws + qkvBytes);
    __bf16* wqb = (__bf16*)((char*)d_ws + qkvBytes + xbBytes);
    __bf16* wob = (__bf16*)((char*)d_ws + qkvBytes + xbBytes + wqBytes);
    cvt_all<<<4096, 256, 0, stream>>>(x, w_qkv, w_o, xb, wqb, wob);
    gemm_bt<__bf16><<<dim3(3072 / 128, MTOT / 128), 256, 0, stream>>>(
        xb, wqb, qkv, MTOT, 3072, DM, DM, 1e4f);
    attn_fwd<<<dim3(16, NH, BATCH), 512, 0, stream>>>(qkv);
    gemm_bt64<float><<<dim3(DM / 128, MTOT / 64), 256, 0, stream>>>(
        qkv, wob, out, MTOT, DM, DM, 3072, 2e4f);
  } else if (ws_size >= qkvBytes) {
    gemm_nt<1, 1, __bf16><<<dim3(3072 / 128, MTOT / 128), 256, 0, stream>>>(
        x, w_qkv, qkv, MTOT, 3072, DM, DM, 1e4f);
    attn_fwd<<<dim3(16, NH, BATCH), 512, 0, stream>>>(qkv);
    gemm_nt<0, 1, float><<<dim3(DM / 128, MTOT / 128), 256, 0, stream>>>(
        qkv, w_o, out, MTOT, DM, DM, 3072, 2e4f);
  } else {
    sentinel_fill<<<256, 256, 0, stream>>>(out, out_size);
  }
}

// Round 13
// 203.873 us; speedup vs baseline: 1.1375x; 1.0225x over previous
//
#include <hip/hip_runtime.h>

constexpr int SEQ = 2048;
constexpr int DM = 1024;
constexpr int NH = 16;
constexpr int BATCH = 2;
constexpr int MTOT = BATCH * SEQ;   // 4096

typedef __bf16 bf16x8 __attribute__((ext_vector_type(8)));
typedef __bf16 bf16x4 __attribute__((ext_vector_type(4)));
typedef float f32x4 __attribute__((ext_vector_type(4)));

#define MFMA16(a, b, c) __builtin_amdgcn_mfma_f32_16x16x32_bf16((a), (b), (c), 0, 0, 0)

__device__ __forceinline__ void async_copy16(const void* g, void* l) {
  __builtin_amdgcn_global_load_lds((const __attribute__((address_space(1))) void*)g,
                                   (__attribute__((address_space(3))) void*)l, 16, 0, 0);
}

// T1 bijective XCD swizzle (R7): contiguous block chunks per XCD. nwg%8==0.
__device__ __forceinline__ void xcd_swizzle(int& bx, int& by) {
  const int gx = gridDim.x;
  const int nwg = gx * gridDim.y;
  const int bid = blockIdx.y * gx + blockIdx.x;
  const int cpx = nwg >> 3;
  const int v = (bid & 7) * cpx + (bid >> 3);
  by = v / gx;
  bx = v - by * gx;
}

__global__ void sentinel_fill(float* out, int n) {
  int i = blockIdx.x * blockDim.x + threadIdx.x;
  for (; i < n; i += gridDim.x * blockDim.x) out[i] = 0.25f;
}

// one-shot fp32 -> bf16 conversion of x, w_qkv, w_o
__global__ __launch_bounds__(256) void cvt_all(const float* __restrict__ x,
                                               const float* __restrict__ wq,
                                               const float* __restrict__ wo,
                                               __bf16* __restrict__ xb,
                                               __bf16* __restrict__ wqb,
                                               __bf16* __restrict__ wob) {
  const long i = (long)(blockIdx.x * 256 + threadIdx.x) * 8;
  const float* src;
  __bf16* dst;
  long off;
  if (i < 4194304) { src = x; dst = xb; off = i; }
  else if (i < 7340032) { src = wq; dst = wqb; off = i - 4194304; }
  else { src = wo; dst = wob; off = i - 7340032; }
  f32x4 lo = *(const f32x4*)(src + off);
  f32x4 hi = *(const f32x4*)(src + off + 4);
  bf16x8 r;
#pragma unroll
  for (int j = 0; j < 4; ++j) { r[j] = (__bf16)lo[j]; r[4 + j] = (__bf16)hi[j]; }
  *(bf16x8*)(dst + off) = r;
}

// FAST GEMM: C[M,N]=A[M,K]*B[N,K]^T, 128x128 tile, m97 fragment geometry.
// R8 counted-vmcnt 3-buffer pipeline + R7 XCD swizzle (verified best, kept).
template <typename OutT>
__global__ __launch_bounds__(256) void gemm_bt(const __bf16* __restrict__ A,
                                               const __bf16* __restrict__ B,
                                               OutT* __restrict__ C,
                                               int M, int N, int K, int lda,
                                               float nanSig) {
  __shared__ alignas(16) __bf16 As[3][128 * 32];
  __shared__ alignas(16) __bf16 Bs[3][128 * 32];
  const int tid = threadIdx.x;
  const int lane = tid & 63;
  const int wave = tid >> 6;
  const int lr = lane & 15;
  const int quad = lane >> 4;
  const int wm = (wave >> 1) * 64;
  const int wn = (wave & 1) * 64;
  int bx, by;
  xcd_swizzle(bx, by);
  const int m0 = by * 128;
  const int n0 = bx * 128;

  const int ra = tid >> 2;
  const int ca = (tid & 3) * 8;
  const __bf16* gA0 = A + (long)(m0 + ra) * lda + ca;
  const __bf16* gA1 = A + (long)(m0 + 64 + ra) * lda + ca;
  const __bf16* gB0 = B + (long)(n0 + ra) * K + ca;
  const __bf16* gB1 = B + (long)(n0 + 64 + ra) * K + ca;

  f32x4 acc[4][4];
#pragma unroll
  for (int i = 0; i < 4; ++i)
#pragma unroll
    for (int j = 0; j < 4; ++j) acc[i][j] = (f32x4){0.f, 0.f, 0.f, 0.f};

  auto stage = [&](int bi, int k0) {
    async_copy16(gA0 + k0, &As[bi][wave * 512]);
    async_copy16(gA1 + k0, &As[bi][2048 + wave * 512]);
    async_copy16(gB0 + k0, &Bs[bi][wave * 512]);
    async_copy16(gB1 + k0, &Bs[bi][2048 + wave * 512]);
  };

  const int nt = K >> 5;
  stage(0, 0);
  if (nt > 1) stage(1, 32);

  int cur = 0;
  for (int t = 0; t < nt; ++t) {
    if (t + 1 < nt) {
      asm volatile("s_waitcnt vmcnt(4)" ::: "memory");
    } else {
      asm volatile("s_waitcnt vmcnt(0)" ::: "memory");
    }
    __builtin_amdgcn_sched_barrier(0);
    __builtin_amdgcn_s_barrier();  // stage(t) visible; buf[(t-1)%3] reads done
    if (t + 2 < nt) stage(cur == 0 ? 2 : cur - 1, (t + 2) * 32);  // (t+2)%3

    bf16x8 af[4], bfr[4];
#pragma unroll
    for (int i = 0; i < 4; ++i)
      af[i] = *(const bf16x8*)&As[cur][(wm + i * 16 + lr) * 32 + quad * 8];
#pragma unroll
    for (int j = 0; j < 4; ++j)
      bfr[j] = *(const bf16x8*)&Bs[cur][(wn + j * 16 + lr) * 32 + quad * 8];
    __builtin_amdgcn_s_setprio(1);
#pragma unroll
    for (int i = 0; i < 4; ++i)
#pragma unroll
      for (int j = 0; j < 4; ++j) acc[i][j] = MFMA16(af[i], bfr[j], acc[i][j]);
    __builtin_amdgcn_s_setprio(0);
    cur = (cur == 2) ? 0 : cur + 1;
  }

#pragma unroll
  for (int i = 0; i < 4; ++i) {
    const int row = m0 + wm + i * 16 + quad * 4;
#pragma unroll
    for (int j = 0; j < 4; ++j) {
      const int col = n0 + wn + j * 16 + lr;
#pragma unroll
      for (int r = 0; r < 4; ++r) {
        float v = acc[i][j][r];
        if (!(v == v)) v = nanSig;
        C[(long)(row + r) * N + col] = (OutT)v;
      }
    }
  }
}

// 64x128-tile variant for gemm2 (R7/R8, kept): 512 blocks = 2/CU,
// counted-vmcnt 3-buffer pipeline. LDS 36 KB.
template <typename OutT>
__global__ __launch_bounds__(256) void gemm_bt64(const __bf16* __restrict__ A,
                                                 const __bf16* __restrict__ B,
                                                 OutT* __restrict__ C,
                                                 int M, int N, int K, int lda,
                                                 float nanSig) {
  __shared__ alignas(16) __bf16 As[3][64 * 32];
  __shared__ alignas(16) __bf16 Bs[3][128 * 32];
  const int tid = threadIdx.x;
  const int lane = tid & 63;
  const int wave = tid >> 6;
  const int lr = lane & 15;
  const int quad = lane >> 4;
  const int wm = (wave >> 1) * 32;
  const int wn = (wave & 1) * 64;
  int bx, by;
  xcd_swizzle(bx, by);
  const int m0 = by * 64;
  const int n0 = bx * 128;

  const int ra = tid >> 2;          // 0..63
  const int ca = (tid & 3) * 8;
  const __bf16* gA0 = A + (long)(m0 + ra) * lda + ca;
  const __bf16* gB0 = B + (long)(n0 + ra) * K + ca;
  const __bf16* gB1 = B + (long)(n0 + 64 + ra) * K + ca;

  f32x4 acc[2][4];
#pragma unroll
  for (int i = 0; i < 2; ++i)
#pragma unroll
    for (int j = 0; j < 4; ++j) acc[i][j] = (f32x4){0.f, 0.f, 0.f, 0.f};

  auto stage = [&](int bi, int k0) {
    async_copy16(gA0 + k0, &As[bi][wave * 512]);
    async_copy16(gB0 + k0, &Bs[bi][wave * 512]);
    async_copy16(gB1 + k0, &Bs[bi][2048 + wave * 512]);
  };

  const int nt = K >> 5;
  stage(0, 0);
  if (nt > 1) stage(1, 32);

  int cur = 0;
  for (int t = 0; t < nt; ++t) {
    if (t + 1 < nt) {
      asm volatile("s_waitcnt vmcnt(3)" ::: "memory");
    } else {
      asm volatile("s_waitcnt vmcnt(0)" ::: "memory");
    }
    __builtin_amdgcn_sched_barrier(0);
    __builtin_amdgcn_s_barrier();
    if (t + 2 < nt) stage(cur == 0 ? 2 : cur - 1, (t + 2) * 32);

    bf16x8 af[2], bfr[4];
#pragma unroll
    for (int i = 0; i < 2; ++i)
      af[i] = *(const bf16x8*)&As[cur][(wm + i * 16 + lr) * 32 + quad * 8];
#pragma unroll
    for (int j = 0; j < 4; ++j)
      bfr[j] = *(const bf16x8*)&Bs[cur][(wn + j * 16 + lr) * 32 + quad * 8];
    __builtin_amdgcn_s_setprio(1);
#pragma unroll
    for (int i = 0; i < 2; ++i)
#pragma unroll
      for (int j = 0; j < 4; ++j) acc[i][j] = MFMA16(af[i], bfr[j], acc[i][j]);
    __builtin_amdgcn_s_setprio(0);
    cur = (cur == 2) ? 0 : cur + 1;
  }

#pragma unroll
  for (int i = 0; i < 2; ++i) {
    const int row = m0 + wm + i * 16 + quad * 4;
#pragma unroll
    for (int j = 0; j < 4; ++j) {
      const int col = n0 + wn + j * 16 + lr;
#pragma unroll
      for (int r = 0; r < 4; ++r) {
        float v = acc[i][j][r];
        if (!(v == v)) v = nanSig;
        C[(long)(row + r) * N + col] = (OutT)v;
      }
    }
  }
}

// SLOW fallback GEMM (inline fp32 cvt, verified R9).
template <int F32>
__device__ __forceinline__ bf16x8 load_cvt8(const void* base, long off) {
  if constexpr (F32) {
    const float* p = (const float*)base + off;
    f32x4 lo = *(const f32x4*)p;
    f32x4 hi = *(const f32x4*)(p + 4);
    bf16x8 r;
#pragma unroll
    for (int j = 0; j < 4; ++j) { r[j] = (__bf16)lo[j]; r[4 + j] = (__bf16)hi[j]; }
    return r;
  } else {
    return *(const bf16x8*)((const __bf16*)base + off);
  }
}

template <int AF32, int BF32, typename OutT>
__global__ __launch_bounds__(256) void gemm_nt(const void* __restrict__ Av,
                                               const void* __restrict__ Bv,
                                               OutT* __restrict__ C,
                                               int M, int N, int K, int lda,
                                               float nanSig) {
  __shared__ alignas(16) __bf16 As[128 * 32];
  __shared__ alignas(16) __bf16 Bs[128 * 32];
  const int tid = threadIdx.x;
  const int lane = tid & 63;
  const int wave = tid >> 6;
  const int lr = lane & 15;
  const int quad = lane >> 4;
  const int wm = (wave >> 1) * 64;
  const int wn = (wave & 1) * 64;
  const int m0 = blockIdx.y * 128;
  const int n0 = blockIdx.x * 128;

  const int r0 = tid >> 2;
  const int r1 = 64 + (tid >> 2);
  const int cc = (tid & 3) * 8;
  const long aBase0 = (long)(m0 + r0) * lda + cc;
  const long aBase1 = (long)(m0 + r1) * lda + cc;
  const long bBase0 = (long)(n0 + r0) * K + cc;
  const long bBase1 = (long)(n0 + r1) * K + cc;
  __bf16* lA0 = &As[r0 * 32 + cc];
  __bf16* lA1 = &As[r1 * 32 + cc];
  __bf16* lB0 = &Bs[r0 * 32 + cc];
  __bf16* lB1 = &Bs[r1 * 32 + cc];

  f32x4 acc[4][4];
#pragma unroll
  for (int i = 0; i < 4; ++i)
#pragma unroll
    for (int j = 0; j < 4; ++j) acc[i][j] = (f32x4){0.f, 0.f, 0.f, 0.f};

  for (int k0 = 0; k0 < K; k0 += 32) {
    bf16x8 va0 = load_cvt8<AF32>(Av, aBase0 + k0);
    bf16x8 va1 = load_cvt8<AF32>(Av, aBase1 + k0);
    bf16x8 vb0 = load_cvt8<BF32>(Bv, bBase0 + k0);
    bf16x8 vb1 = load_cvt8<BF32>(Bv, bBase1 + k0);
    __syncthreads();
    *(bf16x8*)lA0 = va0;
    *(bf16x8*)lA1 = va1;
    *(bf16x8*)lB0 = vb0;
    *(bf16x8*)lB1 = vb1;
    __syncthreads();
    bf16x8 af[4], bfr[4];
#pragma unroll
    for (int i = 0; i < 4; ++i) af[i] = *(const bf16x8*)&As[(wm + i * 16 + lr) * 32 + quad * 8];
#pragma unroll
    for (int j = 0; j < 4; ++j) bfr[j] = *(const bf16x8*)&Bs[(wn + j * 16 + lr) * 32 + quad * 8];
#pragma unroll
    for (int i = 0; i < 4; ++i)
#pragma unroll
      for (int j = 0; j < 4; ++j) acc[i][j] = MFMA16(af[i], bfr[j], acc[i][j]);
  }

#pragma unroll
  for (int i = 0; i < 4; ++i) {
    const int row = m0 + wm + i * 16 + quad * 4;
#pragma unroll
    for (int j = 0; j < 4; ++j) {
      const int col = n0 + wn + j * 16 + lr;
#pragma unroll
      for (int r = 0; r < 4; ++r) {
        float v = acc[i][j][r];
        if (!(v == v)) v = nanSig;
        C[(long)(row + r) * N + col] = (OutT)v;
      }
    }
  }
}

// Flash causal attention, S^T form. R9 QG-PER-WAVE SPLIT + R12 raw-domain
// softmax. R13: ANTI-CORRELATED PAIR ASSIGNMENT — block duration is
// Tb = 32 - pi barrier iterations (17..32, NOT uniform); round-robin dispatch
// co-locates blocks c and c+256 (same blockIdx.x = same pi = same Tb), so
// per-CU iteration count was 2*(32-pi): 64 for pi=0 CUs vs 34 for pi=15 —
// ~30% makespan imbalance in the dominant fixed (staging+barrier) term.
// Fix: pi = (z&1) ? 15-x : x. Co-located pair Tb-sum = (32-p)+(17+p) = 49
// for EVERY CU. Bijective per (h,b) -> coverage identical.
__global__ __launch_bounds__(512, 4) void attn_fwd(__bf16* __restrict__ qkv) {
  const int h = blockIdx.y;
  const int b = blockIdx.z;
  const int pi = (b & 1) ? (15 - blockIdx.x) : blockIdx.x;  // R13 balance remap
  const int q0A = pi * 64;
  const int q0B = (31 - pi) * 64;
  const int tid = threadIdx.x;
  const int lane = tid & 63;
  const int wave = tid >> 6;      // 0..7
  const int grp = wave >> 2;      // 0: q-tile B (full range), 1: q-tile A
  const int q0X = grp ? q0A : q0B;
  const int lr = lane & 15;
  const int quad = lane >> 4;
  const int wq = (wave & 3) * 16;
  const int qi = q0X + wq + lr;

  __shared__ alignas(16) __bf16 Ks[2][64 * 72];  // K rows [kv][d], double-buffered
  __shared__ alignas(16) __bf16 Vt[2][64 * 72];  // V^T [d][kv^swz], double-buffered
  __shared__ alignas(16) __bf16 Pq[128 * 72];    // P [wave*16 + q][kv]

  __bf16* pqw = &Pq[wave * 16 * 72];
  const long base = (long)b * SEQ * 3072;

  // Q as B-operand fragments (one q-group per wave)
  bf16x8 b_q[2];
  {
    const long rowoff = base + (long)qi * 3072 + h * 64;
    b_q[0] = *(const bf16x8*)(qkv + rowoff + quad * 8);
    b_q[1] = *(const bf16x8*)(qkv + rowoff + 32 + quad * 8);
  }

  const float NEGS = -30000.f;       // raw-domain mask value
  const float SC = 0.18033688f;      // 0.125 * log2(e)
  float m_i = NEGS, l_i = 0.f;       // m_i in RAW score domain (R12)
  f32x4 o_acc[4];
#pragma unroll
  for (int dt = 0; dt < 4; ++dt) o_acc[dt] = (f32x4){0.f, 0.f, 0.f, 0.f};

  // staging thread geometry (512 stagers: 1 row each)
  const int r_ = tid >> 3;            // 0..63
  const int col_ = (tid & 7) * 8;     // 0..56
  const int l8 = tid & 7;
  const int sw = (l8 & 3) << 3;       // Vt swizzle amount for this thread's cols
  const bool oddr = (tid >> 3) & 1;
  const int jb = oddr ? 4 : 0;

  const int Tb = 32 - pi;             // B's full causal range in KV tiles, >= 17

  bf16x8 kreg, vreg;
  auto loadTile = [&](int t) {
    const long ro = base + ((long)t * 64 + r_) * 3072 + h * 64 + col_;
    kreg = *(const bf16x8*)(qkv + ro + 1024);
    vreg = *(const bf16x8*)(qkv + ro + 2048);
  };
  auto stageTile = [&](int bi) {
    __bf16* ks = &Ks[bi][0];
    __bf16* vt = &Vt[bi][0];
    // K row -> LDS (b128)
    *(bf16x8*)&ks[r_ * 72 + col_] = kreg;
    // V^T via pair-transpose + swizzle (b32 writes, 2-way banks = free)
    const int rr = (r_ & ~1) ^ sw;
    int vd[4], od[4];
    __builtin_memcpy(vd, &vreg, 16);
#pragma unroll
    for (int i = 0; i < 4; ++i) od[i] = __shfl_xor(vd[i], 8);
#pragma unroll
    for (int i = 0; i < 4; ++i) {
      const int j = jb + i;
      const int a = vd[j >> 1], bb = od[j >> 1];
      const int lo = oddr ? bb : a;
      const int hi = oddr ? a : bb;
      const int pair = (j & 1) ? (int)(((unsigned)lo >> 16) | (hi & 0xffff0000))
                               : (int)((lo & 0xffff) | (hi << 16));
      *(int*)&vt[(col_ + j) * 72 + rr] = pair;
    }
  };

  // prologue: stage tile 0 into buf0, issue loads for tile 1
  loadTile(0);
  stageTile(0);
  loadTile(1);  // Tb >= 17, always valid
  __syncthreads();

  for (int t = 0; t < Tb; ++t) {
    const int cur = t & 1;
    const int kv0 = t * 64;
    // wave-uniform: B-waves always active; A-waves while kv in causal range
    const bool act = (grp == 0) || (kv0 <= q0A + wq + 15);

    // S^T = K * Q^T from Ks[cur]
    f32x4 st[4];
#pragma unroll
    for (int kt = 0; kt < 4; ++kt) st[kt] = (f32x4){0.f, 0.f, 0.f, 0.f};
    if (act) {
      __builtin_amdgcn_s_setprio(1);
#pragma unroll
      for (int ks = 0; ks < 2; ++ks) {
        bf16x8 ak[4];
#pragma unroll
        for (int kt = 0; kt < 4; ++kt)
          ak[kt] = *(const bf16x8*)&Ks[cur][(kt * 16 + lr) * 72 + ks * 32 + quad * 8];
#pragma unroll
        for (int kt = 0; kt < 4; ++kt) st[kt] = MFMA16(ak[kt], b_q[ks], st[kt]);
      }
      __builtin_amdgcn_s_setprio(0);
    }

    // stage tile t+1 into the other buffer (overlaps with softmax below),
    // then issue global loads for tile t+2 (consumed by next iter's stage).
    if (t + 1 < Tb) stageTile(cur ^ 1);
    if (t + 2 < Tb) loadTile(t + 2);

    if (act) {
      // causal mask: select-only, raw domain (no scale mul — R12)
      if (kv0 + 64 > q0X + wq) {
#pragma unroll
        for (int kt = 0; kt < 4; ++kt) {
          const int d0 = kv0 + kt * 16 + quad * 4 - qi;
#pragma unroll
          for (int r = 0; r < 4; ++r)
            st[kt][r] = (d0 + r <= 0) ? st[kt][r] : NEGS;
        }
      }
      // max reduce: pairwise tree (halved dep chain) + 2 shfl
      float t0 = fmaxf(fmaxf(st[0][0], st[0][1]), fmaxf(st[0][2], st[0][3]));
      float t1 = fmaxf(fmaxf(st[1][0], st[1][1]), fmaxf(st[1][2], st[1][3]));
      float t2 = fmaxf(fmaxf(st[2][0], st[2][1]), fmaxf(st[2][2], st[2][3]));
      float t3 = fmaxf(fmaxf(st[3][0], st[3][1]), fmaxf(st[3][2], st[3][3]));
      float mx = fmaxf(fmaxf(t0, t1), fmaxf(t2, t3));
      mx = fmaxf(mx, __shfl_xor(mx, 16));
      mx = fmaxf(mx, __shfl_xor(mx, 32));
      // T13 defer-rescale: raw-domain threshold 8/SC ~= 44.36 -> 44
      const bool noresc = __all(mx - m_i <= 44.f);
      const float mnew = noresc ? m_i : fmaxf(m_i, mx);
      const float msc = mnew * SC;
      float rs = 0.f;
#pragma unroll
      for (int kt = 0; kt < 4; ++kt)
#pragma unroll
        for (int r = 0; r < 4; ++r) {
          const float p = exp2f(fmaf(st[kt][r], SC, -msc));
          st[kt][r] = p;
          rs += p;
        }
      rs += __shfl_xor(rs, 16);
      rs += __shfl_xor(rs, 32);
      // P -> wave-private LDS (b64 writes, 2-way = free)
#pragma unroll
      for (int kt = 0; kt < 4; ++kt) {
        bf16x4 pv;
#pragma unroll
        for (int r = 0; r < 4; ++r) pv[r] = (__bf16)st[kt][r];
        *(bf16x4*)&pqw[lr * 72 + kt * 16 + quad * 4] = pv;
      }
      if (noresc) {
        l_i += rs;
      } else {
        const float alpha = exp2f((m_i - mnew) * SC);
        l_i = l_i * alpha + rs;
        m_i = mnew;
#pragma unroll
        for (int dt = 0; dt < 4; ++dt)
#pragma unroll
          for (int r = 0; r < 4; ++r) o_acc[dt][r] *= alpha;
      }

      // single LDS-only fence: P writes visible to own wave's ds_reads;
      // leaves the depth-2 global prefetch in flight.
      asm volatile("s_waitcnt lgkmcnt(0)" ::: "memory");
      __builtin_amdgcn_sched_barrier(0);

      // O^T += V^T * P^T (swizzled block addressing) from Vt[cur]
      __builtin_amdgcn_s_setprio(1);
#pragma unroll
      for (int ks = 0; ks < 2; ++ks) {
        bf16x8 av[4];
#pragma unroll
        for (int dt = 0; dt < 4; ++dt) {
          const int blk = ((ks << 2) + quad) ^ ((2 * dt + (lr >> 3)) & 3);
          av[dt] = *(const bf16x8*)&Vt[cur][(dt * 16 + lr) * 72 + (blk << 3)];
        }
        bf16x8 bp = *(const bf16x8*)&pqw[lr * 72 + ks * 32 + quad * 8];
#pragma unroll
        for (int dt = 0; dt < 4; ++dt) o_acc[dt] = MFMA16(av[dt], bp, o_acc[dt]);
      }
      __builtin_amdgcn_s_setprio(0);
    }

    __syncthreads();  // single barrier per tile: staging of t+1 visible,
                      // reads of buf[cur] complete before iter t+1 overwrites
  }

  // epilogue: O/l -> q-slice in place (one q-group per wave)
  {
    const float inv = 1.f / fmaxf(l_i, 1e-30f);
    const long obase = base + (long)qi * 3072 + h * 64 + quad * 4;
#pragma unroll
    for (int dt = 0; dt < 4; ++dt) {
      bf16x4 ov;
#pragma unroll
      for (int r = 0; r < 4; ++r) ov[r] = (__bf16)(o_acc[dt][r] * inv);
      *(bf16x4*)(qkv + obase + dt * 16) = ov;
    }
  }
}

extern "C" void kernel_launch(void* const* d_in, const int* in_sizes, int n_in,
                              void* d_out, int out_size, void* d_ws, size_t ws_size,
                              hipStream_t stream) {
  const float* x = (const float*)d_in[0];
  const float* w_qkv = (const float*)d_in[1];
  const float* w_o = (const float*)d_in[2];
  for (int i = 0; i < n_in; ++i) {
    if (in_sizes[i] == MTOT * DM) x = (const float*)d_in[i];
    else if (in_sizes[i] == 3 * DM * DM) w_qkv = (const float*)d_in[i];
    else if (in_sizes[i] == DM * DM) w_o = (const float*)d_in[i];
  }
  float* out = (float*)d_out;  // FP32 output per reference dtype

  const size_t qkvBytes = (size_t)MTOT * 3072 * 2;       // 24 MiB
  const size_t xbBytes = (size_t)MTOT * DM * 2;          // 8 MiB
  const size_t wqBytes = (size_t)3 * DM * DM * 2;        // 6 MiB
  const size_t woBytes = (size_t)DM * DM * 2;            // 2 MiB
  const size_t needFast = qkvBytes + xbBytes + wqBytes + woBytes;  // 40 MiB

  __bf16* qkv = (__bf16*)d_ws;

  if (ws_size >= needFast) {
    __bf16* xb = (__bf16*)((char*)d_ws + qkvBytes);
    __bf16* wqb = (__bf16*)((char*)d_ws + qkvBytes + xbBytes);
    __bf16* wob = (__bf16*)((char*)d_ws + qkvBytes + xbBytes + wqBytes);
    cvt_all<<<4096, 256, 0, stream>>>(x, w_qkv, w_o, xb, wqb, wob);
    gemm_bt<__bf16><<<dim3(3072 / 128, MTOT / 128), 256, 0, stream>>>(
        xb, wqb, qkv, MTOT, 3072, DM, DM, 1e4f);
    attn_fwd<<<dim3(16, NH, BATCH), 512, 0, stream>>>(qkv);
    gemm_bt64<float><<<dim3(DM / 128, MTOT / 64), 256, 0, stream>>>(
        qkv, wob, out, MTOT, DM, DM, 3072, 2e4f);
  } else if (ws_size >= qkvBytes) {
    gemm_nt<1, 1, __bf16><<<dim3(3072 / 128, MTOT / 128), 256, 0, stream>>>(
        x, w_qkv, qkv, MTOT, 3072, DM, DM, 1e4f);
    attn_fwd<<<dim3(16, NH, BATCH), 512, 0, stream>>>(qkv);
    gemm_nt<0, 1, float><<<dim3(DM / 128, MTOT / 128), 256, 0, stream>>>(
        qkv, w_o, out, MTOT, DM, DM, 3072, 2e4f);
  } else {
    sentinel_fill<<<256, 256, 0, stream>>>(out, out_size);
  }
}